// Round 1
// baseline (352.173 us; speedup 1.0000x reference)
//
#include <hip/hip_runtime.h>
#include <hip/hip_bf16.h>
#include <hip/hip_fp16.h>

#define N_B 16
#define C_DIM 256
#define HW 4096
#define K_A 512
#define M_TOT (N_B*HW)          // 65536 global rows
#define TEMP_INV (1.0f/0.3f)
#define EPS_SK 1e-12f

typedef _Float16 f16x8 __attribute__((ext_vector_type(8)));
typedef float f32x4 __attribute__((ext_vector_type(4)));

// ---------------- init u=1, v=1 ----------------
__global__ __launch_bounds__(256) void k_init(float* u, float* v){
    int i = blockIdx.x*256 + threadIdx.x;
    if (i < M_TOT) u[i] = 1.0f;
    if (i < K_A)   v[i] = 1.0f;
}

// ---------------- channel L2 norms: invn[n*HW+hw] ----------------
__global__ __launch_bounds__(256) void k_norm(const float* __restrict__ x, float* __restrict__ invn){
    __shared__ float red[4][64];
    int n   = blockIdx.x >> 6;            // 1024 blocks: 16 n * 64 hw-chunks
    int hw0 = (blockIdx.x & 63) * 64;
    int tx = threadIdx.x & 63, ty = threadIdx.x >> 6;
    const float* px = x + ((size_t)(n*C_DIM + ty))*HW + hw0 + tx;
    float ss = 0.f;
    #pragma unroll 16
    for (int c = 0; c < 64; ++c){ float t = px[(size_t)(c*4)*HW]; ss += t*t; }
    red[ty][tx] = ss;
    __syncthreads();
    if (ty == 0){
        float s = red[0][tx]+red[1][tx]+red[2][tx]+red[3][tx];
        invn[n*HW + hw0 + tx] = 1.0f / fmaxf(sqrtf(s), 1e-12f);
    }
}

// ---------------- transpose + normalize + fp16: Lt[n][hw][c] ----------------
__global__ __launch_bounds__(256) void k_transpose(const float* __restrict__ x,
                                                   const float* __restrict__ invn,
                                                   _Float16* __restrict__ Lt){
    __shared__ float tile[64][65];
    int n   = blockIdx.z;
    int hw0 = blockIdx.x * 64;
    int c0  = blockIdx.y * 64;
    int tx = threadIdx.x & 63, ty = threadIdx.x >> 6;
    float inv = invn[n*HW + hw0 + tx];
    const float* px = x + ((size_t)(n*C_DIM + c0))*HW + hw0 + tx;
    #pragma unroll
    for (int r = 0; r < 16; ++r){
        int cl = ty + r*4;
        tile[cl][tx] = px[(size_t)cl*HW] * inv;
    }
    __syncthreads();
    #pragma unroll
    for (int r = 0; r < 16; ++r){
        int hwl = ty + r*4;
        Lt[((size_t)(n*HW + hw0 + hwl))*C_DIM + c0 + tx] = (_Float16)tile[tx][hwl];
    }
}

// ---------------- gather anchors: sxT[n][j][c] fp16, sx[n][c][j] fp32 ----------------
__global__ __launch_bounds__(256) void k_gather(const float* __restrict__ x,
                                                const float* __restrict__ invn,
                                                const int* __restrict__ sidx,
                                                _Float16* __restrict__ sxT,
                                                float* __restrict__ sx){
    int j = blockIdx.x, n = blockIdx.y, c = threadIdx.x;
    int p = sidx[j];
    float inv = invn[n*HW + p];
    float val = x[((size_t)(n*C_DIM + c))*HW + p] * inv;
    sxT[((size_t)(n*K_A + j))*C_DIM + c] = (_Float16)val;
    sx [((size_t)(n*C_DIM + c))*K_A + j] = val;
}

// ---------------- GEMM1: A0[n*HW+hw][j] = exp(score/T), fp16 out ----------------
// per n: [4096(M=hw) x 256(K=c)] * [256 x 512(N=j)], A = Lt (M-major K-contig),
// B^T = sxT (N-major K-contig). 128x128 tile, 4 waves 2x2, BK=32.
__global__ __launch_bounds__(256) void k_gemm1(const _Float16* __restrict__ Lt,
                                               const _Float16* __restrict__ sxT,
                                               _Float16* __restrict__ A0){
    __shared__ _Float16 As[128*32];
    __shared__ _Float16 Bs[128*32];
    const int nb = blockIdx.z;
    const int mbase = blockIdx.x * 128;
    const int jbase = blockIdx.y * 128;
    const int t = threadIdx.x;
    const int lane = t & 63, w = t >> 6;
    const int wm = (w >> 1)*64, wn = (w & 1)*64;
    const int l15 = lane & 15, lq = lane >> 4;

    f32x4 acc[4][4] = {};
    const _Float16* pa = Lt  + ((size_t)(nb*HW  + mbase))*C_DIM;
    const _Float16* pb = sxT + ((size_t)(nb*K_A + jbase))*C_DIM;

    for (int kt = 0; kt < 8; ++kt){
        int k0 = kt*32;
        #pragma unroll
        for (int q = 0; q < 2; ++q){
            int cid = q*256 + t;           // 512 chunks of 16B
            int row = cid >> 2, ko = (cid & 3)*8;
            *(int4*)&As[cid*8] = *(const int4*)&pa[(size_t)row*C_DIM + k0 + ko];
            *(int4*)&Bs[cid*8] = *(const int4*)&pb[(size_t)row*C_DIM + k0 + ko];
        }
        __syncthreads();
        f16x8 af[4], bf[4];
        #pragma unroll
        for (int mi = 0; mi < 4; ++mi) af[mi] = *(const f16x8*)&As[(wm + mi*16 + l15)*32 + lq*8];
        #pragma unroll
        for (int ni = 0; ni < 4; ++ni) bf[ni] = *(const f16x8*)&Bs[(wn + ni*16 + l15)*32 + lq*8];
        #pragma unroll
        for (int mi = 0; mi < 4; ++mi)
            #pragma unroll
            for (int ni = 0; ni < 4; ++ni)
                acc[mi][ni] = __builtin_amdgcn_mfma_f32_16x16x32_f16(af[mi], bf[ni], acc[mi][ni], 0, 0, 0);
        __syncthreads();
    }
    #pragma unroll
    for (int mi = 0; mi < 4; ++mi)
        #pragma unroll
        for (int ni = 0; ni < 4; ++ni)
            #pragma unroll
            for (int r = 0; r < 4; ++r){
                int hw = mbase + wm + mi*16 + lq*4 + r;   // D row = M
                int j  = jbase + wn + ni*16 + l15;        // D col = N
                float e = __expf(acc[mi][ni][r] * TEMP_INV);
                A0[((size_t)(nb*HW + hw))*K_A + j] = (_Float16)e;
            }
}

// ---------------- Sinkhorn column pass: part[b][j] = sum_{i in chunk} A0[i][j]*u[i] ----------------
__global__ __launch_bounds__(256) void k_colpass(const _Float16* __restrict__ A0,
                                                 const float* __restrict__ u,
                                                 float* __restrict__ part){
    __shared__ float red[4][512];
    int b = blockIdx.x;                         // 512 blocks, 128 rows each
    int tg = threadIdx.x >> 6, lane = threadIdx.x & 63;
    float acc[8] = {};
    for (int it = 0; it < 32; ++it){
        int i = (b << 7) + (it << 2) + tg;
        f16x8 a = *(const f16x8*)&A0[(size_t)i*K_A + (lane << 3)];
        float ui = u[i];
        #pragma unroll
        for (int e = 0; e < 8; ++e) acc[e] += (float)a[e] * ui;
    }
    #pragma unroll
    for (int e = 0; e < 8; ++e) red[tg][(lane<<3)+e] = acc[e];
    __syncthreads();
    if (tg == 0){
        #pragma unroll
        for (int e = 0; e < 8; ++e){
            int j = (lane<<3)+e;
            part[((size_t)b << 9) + j] = red[0][j]+red[1][j]+red[2][j]+red[3][j];
        }
    }
}

// v[j] <- 128 * v[j] / max(v[j]*S_j, EPS)   (gamma=128 keeps magnitudes O(1); exact-equivalent)
__global__ __launch_bounds__(256) void k_colfinish(const float* __restrict__ part, float* __restrict__ v){
    int j = blockIdx.x*256 + threadIdx.x;
    float s = 0.f;
    for (int r = 0; r < 512; ++r) s += part[(size_t)r*K_A + j];
    float vo = v[j];
    v[j] = 128.0f * vo / fmaxf(vo * s, EPS_SK);
}

// ---------------- Sinkhorn row pass: u[i] <- u/max(u*R_i, EPS), R_i = sum_j A0[i][j]*v[j] ----------------
__global__ __launch_bounds__(256) void k_rowpass(const _Float16* __restrict__ A0,
                                                 const float* __restrict__ v,
                                                 float* __restrict__ u){
    int wid  = (blockIdx.x << 2) + (threadIdx.x >> 6);   // one wave per row
    int lane = threadIdx.x & 63;
    f16x8 a = *(const f16x8*)&A0[(size_t)wid*K_A + (lane << 3)];
    const float* pv = v + (lane << 3);
    float r = 0.f;
    #pragma unroll
    for (int e = 0; e < 8; ++e) r += (float)a[e] * pv[e];
    #pragma unroll
    for (int off = 32; off; off >>= 1) r += __shfl_xor(r, off);
    if (lane == 0){
        float uo = u[wid];
        u[wid] = uo / fmaxf(uo * r, EPS_SK);
    }
}

// ---------------- SXv[n][c][j] = sx * v[j], fp16 ----------------
__global__ __launch_bounds__(256) void k_sxv(const float* __restrict__ sx,
                                             const float* __restrict__ v,
                                             _Float16* __restrict__ SXv){
    int i = blockIdx.x*256 + threadIdx.x;
    SXv[i] = (_Float16)(sx[i] * v[i & (K_A-1)]);
}

// ---------------- GEMM2: out[n][c][hw] = u[n*HW+hw] * sum_j SXv[c][j]*A0[hw][j] ----------------
// per n: M=256(c), N=4096(hw), K=512(j). A = SXv (M-major K-contig), B^T = A0 (N-major K-contig).
__global__ __launch_bounds__(256) void k_gemm2(const _Float16* __restrict__ SXv,
                                               const _Float16* __restrict__ A0,
                                               const float* __restrict__ u,
                                               float* __restrict__ out){
    __shared__ _Float16 As[128*32];
    __shared__ _Float16 Bs[128*32];
    const int nb = blockIdx.z;
    const int mbase = blockIdx.x * 128;   // c
    const int nbase = blockIdx.y * 128;   // hw
    const int t = threadIdx.x;
    const int lane = t & 63, w = t >> 6;
    const int wm = (w >> 1)*64, wn = (w & 1)*64;
    const int l15 = lane & 15, lq = lane >> 4;

    f32x4 acc[4][4] = {};
    const _Float16* pa = SXv + ((size_t)(nb*C_DIM + mbase))*K_A;
    const _Float16* pb = A0  + ((size_t)(nb*HW   + nbase))*K_A;

    for (int kt = 0; kt < 16; ++kt){
        int k0 = kt*32;
        #pragma unroll
        for (int q = 0; q < 2; ++q){
            int cid = q*256 + t;
            int row = cid >> 2, ko = (cid & 3)*8;
            *(int4*)&As[cid*8] = *(const int4*)&pa[(size_t)row*K_A + k0 + ko];
            *(int4*)&Bs[cid*8] = *(const int4*)&pb[(size_t)row*K_A + k0 + ko];
        }
        __syncthreads();
        f16x8 af[4], bf[4];
        #pragma unroll
        for (int mi = 0; mi < 4; ++mi) af[mi] = *(const f16x8*)&As[(wm + mi*16 + l15)*32 + lq*8];
        #pragma unroll
        for (int ni = 0; ni < 4; ++ni) bf[ni] = *(const f16x8*)&Bs[(wn + ni*16 + l15)*32 + lq*8];
        #pragma unroll
        for (int mi = 0; mi < 4; ++mi)
            #pragma unroll
            for (int ni = 0; ni < 4; ++ni)
                acc[mi][ni] = __builtin_amdgcn_mfma_f32_16x16x32_f16(af[mi], bf[ni], acc[mi][ni], 0, 0, 0);
        __syncthreads();
    }
    #pragma unroll
    for (int mi = 0; mi < 4; ++mi)
        #pragma unroll
        for (int ni = 0; ni < 4; ++ni)
            #pragma unroll
            for (int r = 0; r < 4; ++r){
                int c  = mbase + wm + mi*16 + lq*4 + r;
                int hw = nbase + wn + ni*16 + l15;
                float val = acc[mi][ni][r] * u[nb*HW + hw];
                out[((size_t)(nb*C_DIM + c))*HW + hw] = val;
            }
}

extern "C" void kernel_launch(void* const* d_in, const int* in_sizes, int n_in,
                              void* d_out, int out_size, void* d_ws, size_t ws_size,
                              hipStream_t stream){
    const float* x  = (const float*)d_in[0];
    const int* sidx = (const int*)d_in[1];
    float* out = (float*)d_out;

    char* ws = (char*)d_ws;
    _Float16* Lt  = (_Float16*)ws;  ws += (size_t)N_B*HW*C_DIM*2;      // 32 MiB
    _Float16* A0  = (_Float16*)ws;  ws += (size_t)M_TOT*K_A*2;         // 64 MiB
    _Float16* sxT = (_Float16*)ws;  ws += (size_t)N_B*K_A*C_DIM*2;     // 4 MiB
    float*    sx  = (float*)ws;     ws += (size_t)N_B*C_DIM*K_A*4;     // 8 MiB
    _Float16* SXv = (_Float16*)ws;  ws += (size_t)N_B*C_DIM*K_A*2;     // 4 MiB
    float*    invn= (float*)ws;     ws += (size_t)M_TOT*4;
    float*    u   = (float*)ws;     ws += (size_t)M_TOT*4;
    float*    v   = (float*)ws;     ws += (size_t)K_A*4;
    float*    part= (float*)ws;     ws += (size_t)512*K_A*4;           // 1 MiB

    k_init     <<<256, 256, 0, stream>>>(u, v);
    k_norm     <<<1024, 256, 0, stream>>>(x, invn);
    k_transpose<<<dim3(64,4,16), 256, 0, stream>>>(x, invn, Lt);
    k_gather   <<<dim3(512,16), 256, 0, stream>>>(x, invn, sidx, sxT, sx);
    k_gemm1    <<<dim3(32,4,16), 256, 0, stream>>>(Lt, sxT, A0);
    for (int it = 0; it < 4; ++it){
        k_colpass  <<<512, 256, 0, stream>>>(A0, u, part);
        k_colfinish<<<2, 256, 0, stream>>>(part, v);
        k_rowpass  <<<16384, 256, 0, stream>>>(A0, v, u);
    }
    k_sxv  <<<8192, 256, 0, stream>>>(sx, v, SXv);
    k_gemm2<<<dim3(2,32,16), 256, 0, stream>>>(SXv, A0, u, out);
}

// Round 2
// 240.370 us; speedup vs baseline: 1.4651x; 1.4651x over previous
//
#include <hip/hip_runtime.h>
#include <hip/hip_bf16.h>
#include <hip/hip_fp16.h>

#define N_B 16
#define C_DIM 256
#define HW 4096
#define K_A 512
#define M_TOT (N_B*HW)          // 65536 global rows
#define TEMP_INV (1.0f/0.3f)
#define EPS_SK 1e-12f

typedef _Float16 f16x8 __attribute__((ext_vector_type(8)));
typedef float f32x4 __attribute__((ext_vector_type(4)));

// ---------------- init u=1, v=1 ----------------
__global__ __launch_bounds__(256) void k_init(float* u, float* v){
    int i = blockIdx.x*256 + threadIdx.x;
    if (i < M_TOT) u[i] = 1.0f;
    if (i < K_A)   v[i] = 1.0f;
}

// ---------------- channel L2 norms: invn[n*HW+hw] ----------------
__global__ __launch_bounds__(256) void k_norm(const float* __restrict__ x, float* __restrict__ invn){
    __shared__ float red[4][64];
    int n   = blockIdx.x >> 6;            // 1024 blocks: 16 n * 64 hw-chunks
    int hw0 = (blockIdx.x & 63) * 64;
    int tx = threadIdx.x & 63, ty = threadIdx.x >> 6;
    const float* px = x + ((size_t)(n*C_DIM + ty))*HW + hw0 + tx;
    float ss = 0.f;
    #pragma unroll 16
    for (int c = 0; c < 64; ++c){ float t = px[(size_t)(c*4)*HW]; ss += t*t; }
    red[ty][tx] = ss;
    __syncthreads();
    if (ty == 0){
        float s = red[0][tx]+red[1][tx]+red[2][tx]+red[3][tx];
        invn[n*HW + hw0 + tx] = 1.0f / fmaxf(sqrtf(s), 1e-12f);
    }
}

// ---------------- transpose + normalize + fp16: Lt[n][hw][c] ----------------
__global__ __launch_bounds__(256) void k_transpose(const float* __restrict__ x,
                                                   const float* __restrict__ invn,
                                                   _Float16* __restrict__ Lt){
    __shared__ float tile[64][65];
    int n   = blockIdx.z;
    int hw0 = blockIdx.x * 64;
    int c0  = blockIdx.y * 64;
    int tx = threadIdx.x & 63, ty = threadIdx.x >> 6;
    float inv = invn[n*HW + hw0 + tx];
    const float* px = x + ((size_t)(n*C_DIM + c0))*HW + hw0 + tx;
    #pragma unroll
    for (int r = 0; r < 16; ++r){
        int cl = ty + r*4;
        tile[cl][tx] = px[(size_t)cl*HW] * inv;
    }
    __syncthreads();
    #pragma unroll
    for (int r = 0; r < 16; ++r){
        int hwl = ty + r*4;
        Lt[((size_t)(n*HW + hw0 + hwl))*C_DIM + c0 + tx] = (_Float16)tile[tx][hwl];
    }
}

// ---------------- gather anchors from Lt (coalesced): sxT[n][j][c] fp16 ----------------
__global__ __launch_bounds__(256) void k_gather(const _Float16* __restrict__ Lt,
                                                const int* __restrict__ sidx,
                                                _Float16* __restrict__ sxT){
    int n  = blockIdx.y;
    int jj = blockIdx.x*8 + (threadIdx.x >> 5);   // 8 anchors per block
    int c8 = (threadIdx.x & 31) * 8;
    int p  = sidx[jj];
    *(f16x8*)&sxT[((size_t)(n*K_A + jj))*C_DIM + c8] =
        *(const f16x8*)&Lt[((size_t)(n*HW + p))*C_DIM + c8];
}

// ---------------- GEMM1: A0[n*HW+hw][j] = exp(score/T), fp16 out ----------------
__global__ __launch_bounds__(256) void k_gemm1(const _Float16* __restrict__ Lt,
                                               const _Float16* __restrict__ sxT,
                                               _Float16* __restrict__ A0){
    __shared__ _Float16 As[128*32];
    __shared__ _Float16 Bs[128*32];
    const int nb = blockIdx.z;
    const int mbase = blockIdx.x * 128;
    const int jbase = blockIdx.y * 128;
    const int t = threadIdx.x;
    const int lane = t & 63, w = t >> 6;
    const int wm = (w >> 1)*64, wn = (w & 1)*64;
    const int l15 = lane & 15, lq = lane >> 4;

    f32x4 acc[4][4] = {};
    const _Float16* pa = Lt  + ((size_t)(nb*HW  + mbase))*C_DIM;
    const _Float16* pb = sxT + ((size_t)(nb*K_A + jbase))*C_DIM;

    for (int kt = 0; kt < 8; ++kt){
        int k0 = kt*32;
        #pragma unroll
        for (int q = 0; q < 2; ++q){
            int cid = q*256 + t;           // 512 chunks of 16B
            int row = cid >> 2, ko = (cid & 3)*8;
            *(int4*)&As[cid*8] = *(const int4*)&pa[(size_t)row*C_DIM + k0 + ko];
            *(int4*)&Bs[cid*8] = *(const int4*)&pb[(size_t)row*C_DIM + k0 + ko];
        }
        __syncthreads();
        f16x8 af[4], bf[4];
        #pragma unroll
        for (int mi = 0; mi < 4; ++mi) af[mi] = *(const f16x8*)&As[(wm + mi*16 + l15)*32 + lq*8];
        #pragma unroll
        for (int ni = 0; ni < 4; ++ni) bf[ni] = *(const f16x8*)&Bs[(wn + ni*16 + l15)*32 + lq*8];
        #pragma unroll
        for (int mi = 0; mi < 4; ++mi)
            #pragma unroll
            for (int ni = 0; ni < 4; ++ni)
                acc[mi][ni] = __builtin_amdgcn_mfma_f32_16x16x32_f16(af[mi], bf[ni], acc[mi][ni], 0, 0, 0);
        __syncthreads();
    }
    #pragma unroll
    for (int mi = 0; mi < 4; ++mi)
        #pragma unroll
        for (int ni = 0; ni < 4; ++ni)
            #pragma unroll
            for (int r = 0; r < 4; ++r){
                int hw = mbase + wm + mi*16 + lq*4 + r;   // D row = M
                int j  = jbase + wn + ni*16 + l15;        // D col = N
                float e = __expf(acc[mi][ni][r] * TEMP_INV);
                A0[((size_t)(nb*HW + hw))*K_A + j] = (_Float16)e;
            }
}

// ---------------- Sinkhorn column pass: part[b][j] = sum_{i in chunk} A0[i][j]*u[i] ----------------
__global__ __launch_bounds__(256) void k_colpass(const _Float16* __restrict__ A0,
                                                 const float* __restrict__ u,
                                                 float* __restrict__ part){
    __shared__ float red[4][512];
    int b = blockIdx.x;                         // 512 blocks, 128 rows each
    int tg = threadIdx.x >> 6, lane = threadIdx.x & 63;
    float acc[8] = {};
    for (int it = 0; it < 32; ++it){
        int i = (b << 7) + (it << 2) + tg;
        f16x8 a = *(const f16x8*)&A0[(size_t)i*K_A + (lane << 3)];
        float ui = u[i];
        #pragma unroll
        for (int e = 0; e < 8; ++e) acc[e] += (float)a[e] * ui;
    }
    #pragma unroll
    for (int e = 0; e < 8; ++e) red[tg][(lane<<3)+e] = acc[e];
    __syncthreads();
    if (tg == 0){
        #pragma unroll
        for (int e = 0; e < 8; ++e){
            int j = (lane<<3)+e;
            part[((size_t)b << 9) + j] = red[0][j]+red[1][j]+red[2][j]+red[3][j];
        }
    }
}

// v[j] <- 128 * v[j] / max(v[j]*S_j, EPS), one wave per j, parallel over the 512 partials
__global__ __launch_bounds__(64) void k_colfinish(const float* __restrict__ part, float* __restrict__ v){
    int j = blockIdx.x;
    int lane = threadIdx.x;
    float s = 0.f;
    #pragma unroll
    for (int e = 0; e < 8; ++e) s += part[((size_t)(lane + e*64) << 9) + j];
    #pragma unroll
    for (int off = 32; off; off >>= 1) s += __shfl_xor(s, off);
    if (lane == 0){
        float vo = v[j];
        v[j] = 128.0f * vo / fmaxf(vo * s, EPS_SK);
    }
}

// ---------------- Sinkhorn row pass: 16 rows per wave, v cached in registers ----------------
__global__ __launch_bounds__(256) void k_rowpass(const _Float16* __restrict__ A0,
                                                 const float* __restrict__ v,
                                                 float* __restrict__ u){
    int wv   = (blockIdx.x << 2) + (threadIdx.x >> 6);   // 4096 waves
    int lane = threadIdx.x & 63;
    float vr[8];
    const float* pv = v + (lane << 3);
    #pragma unroll
    for (int e = 0; e < 8; ++e) vr[e] = pv[e];
    int i0 = wv << 4;
    for (int rr = 0; rr < 16; ++rr){
        int i = i0 + rr;
        f16x8 a = *(const f16x8*)&A0[(size_t)i*K_A + (lane << 3)];
        float r = 0.f;
        #pragma unroll
        for (int e = 0; e < 8; ++e) r += (float)a[e] * vr[e];
        #pragma unroll
        for (int off = 32; off; off >>= 1) r += __shfl_xor(r, off);
        if (lane == 0){
            float uo = u[i];
            u[i] = uo / fmaxf(uo * r, EPS_SK);
        }
    }
}

// ---------------- SXv[n][c][j] = sxT[n][j][c] * v[j]  (LDS transpose, fp16) ----------------
__global__ __launch_bounds__(256) void k_sxvT(const _Float16* __restrict__ sxT,
                                              const float* __restrict__ v,
                                              _Float16* __restrict__ SXv){
    __shared__ float tl[64][65];
    int n  = blockIdx.z;
    int j0 = blockIdx.x * 64;
    int c0 = blockIdx.y * 64;
    int tx = threadIdx.x & 63, ty = threadIdx.x >> 6;
    #pragma unroll
    for (int r = 0; r < 16; ++r){
        int jl = ty + r*4;
        tl[jl][tx] = (float)sxT[((size_t)(n*K_A + j0 + jl))*C_DIM + c0 + tx] * v[j0 + jl];
    }
    __syncthreads();
    #pragma unroll
    for (int r = 0; r < 16; ++r){
        int cl = ty + r*4;
        SXv[((size_t)(n*C_DIM + c0 + cl))*K_A + j0 + tx] = (_Float16)tl[tx][cl];
    }
}

// ---------------- GEMM2: out[n][c][hw] = u[n*HW+hw] * sum_j SXv[c][j]*A0[hw][j] ----------------
__global__ __launch_bounds__(256) void k_gemm2(const _Float16* __restrict__ SXv,
                                               const _Float16* __restrict__ A0,
                                               const float* __restrict__ u,
                                               float* __restrict__ out){
    __shared__ _Float16 As[128*32];
    __shared__ _Float16 Bs[128*32];
    const int nb = blockIdx.z;
    const int mbase = blockIdx.x * 128;   // c
    const int nbase = blockIdx.y * 128;   // hw
    const int t = threadIdx.x;
    const int lane = t & 63, w = t >> 6;
    const int wm = (w >> 1)*64, wn = (w & 1)*64;
    const int l15 = lane & 15, lq = lane >> 4;

    f32x4 acc[4][4] = {};
    const _Float16* pa = SXv + ((size_t)(nb*C_DIM + mbase))*K_A;
    const _Float16* pb = A0  + ((size_t)(nb*HW   + nbase))*K_A;

    for (int kt = 0; kt < 16; ++kt){
        int k0 = kt*32;
        #pragma unroll
        for (int q = 0; q < 2; ++q){
            int cid = q*256 + t;
            int row = cid >> 2, ko = (cid & 3)*8;
            *(int4*)&As[cid*8] = *(const int4*)&pa[(size_t)row*K_A + k0 + ko];
            *(int4*)&Bs[cid*8] = *(const int4*)&pb[(size_t)row*K_A + k0 + ko];
        }
        __syncthreads();
        f16x8 af[4], bf[4];
        #pragma unroll
        for (int mi = 0; mi < 4; ++mi) af[mi] = *(const f16x8*)&As[(wm + mi*16 + l15)*32 + lq*8];
        #pragma unroll
        for (int ni = 0; ni < 4; ++ni) bf[ni] = *(const f16x8*)&Bs[(wn + ni*16 + l15)*32 + lq*8];
        #pragma unroll
        for (int mi = 0; mi < 4; ++mi)
            #pragma unroll
            for (int ni = 0; ni < 4; ++ni)
                acc[mi][ni] = __builtin_amdgcn_mfma_f32_16x16x32_f16(af[mi], bf[ni], acc[mi][ni], 0, 0, 0);
        __syncthreads();
    }
    #pragma unroll
    for (int mi = 0; mi < 4; ++mi)
        #pragma unroll
        for (int ni = 0; ni < 4; ++ni)
            #pragma unroll
            for (int r = 0; r < 4; ++r){
                int c  = mbase + wm + mi*16 + lq*4 + r;
                int hw = nbase + wn + ni*16 + l15;
                float val = acc[mi][ni][r] * u[nb*HW + hw];
                out[((size_t)(nb*C_DIM + c))*HW + hw] = val;
            }
}

extern "C" void kernel_launch(void* const* d_in, const int* in_sizes, int n_in,
                              void* d_out, int out_size, void* d_ws, size_t ws_size,
                              hipStream_t stream){
    const float* x  = (const float*)d_in[0];
    const int* sidx = (const int*)d_in[1];
    float* out = (float*)d_out;

    char* ws = (char*)d_ws;
    _Float16* Lt  = (_Float16*)ws;  ws += (size_t)N_B*HW*C_DIM*2;      // 32 MiB
    _Float16* A0  = (_Float16*)ws;  ws += (size_t)M_TOT*K_A*2;         // 64 MiB
    _Float16* sxT = (_Float16*)ws;  ws += (size_t)N_B*K_A*C_DIM*2;     // 4 MiB
    _Float16* SXv = (_Float16*)ws;  ws += (size_t)N_B*C_DIM*K_A*2;     // 4 MiB
    float*    invn= (float*)ws;     ws += (size_t)M_TOT*4;
    float*    u   = (float*)ws;     ws += (size_t)M_TOT*4;
    float*    v   = (float*)ws;     ws += (size_t)K_A*4;
    float*    part= (float*)ws;     ws += (size_t)512*K_A*4;           // 1 MiB

    k_init     <<<256, 256, 0, stream>>>(u, v);
    k_norm     <<<1024, 256, 0, stream>>>(x, invn);
    k_transpose<<<dim3(64,4,16), 256, 0, stream>>>(x, invn, Lt);
    k_gather   <<<dim3(64,16), 256, 0, stream>>>(Lt, sidx, sxT);
    k_gemm1    <<<dim3(32,4,16), 256, 0, stream>>>(Lt, sxT, A0);
    for (int it = 0; it < 4; ++it){
        k_colpass  <<<512, 256, 0, stream>>>(A0, u, part);
        k_colfinish<<<512, 64, 0, stream>>>(part, v);
        k_rowpass  <<<1024, 256, 0, stream>>>(A0, v, u);
    }
    k_sxvT <<<dim3(8,4,16), 256, 0, stream>>>(sxT, v, SXv);
    k_gemm2<<<dim3(2,32,16), 256, 0, stream>>>(SXv, A0, u, out);
}

// Round 3
// 217.131 us; speedup vs baseline: 1.6219x; 1.1070x over previous
//
#include <hip/hip_runtime.h>
#include <hip/hip_bf16.h>
#include <hip/hip_fp16.h>

#define N_B 16
#define C_DIM 256
#define HW 4096
#define K_A 512
#define M_TOT (N_B*HW)          // 65536 global rows
#define TEMP_INV (1.0f/0.3f)
#define EPS_SK 1e-12f

typedef _Float16 f16x8 __attribute__((ext_vector_type(8)));
typedef float f32x4 __attribute__((ext_vector_type(4)));

#define GLOBAL_AS __attribute__((address_space(1)))
#define LDS_AS __attribute__((address_space(3)))
__device__ __forceinline__ void gload_lds16(const void* g, void* l){
    __builtin_amdgcn_global_load_lds((GLOBAL_AS const void*)g, (LDS_AS void*)l, 16, 0, 0);
}

// ---------------- init u=1, v=1 ----------------
__global__ __launch_bounds__(256) void k_init(float* u, float* v){
    int i = blockIdx.x*256 + threadIdx.x;
    if (i < M_TOT) u[i] = 1.0f;
    if (i < K_A)   v[i] = 1.0f;
}

// ---------------- channel L2 norms: invn[n*HW+hw] ----------------
__global__ __launch_bounds__(256) void k_norm(const float* __restrict__ x, float* __restrict__ invn){
    __shared__ float red[4][64];
    int n   = blockIdx.x >> 6;
    int hw0 = (blockIdx.x & 63) * 64;
    int tx = threadIdx.x & 63, ty = threadIdx.x >> 6;
    const float* px = x + ((size_t)(n*C_DIM + ty))*HW + hw0 + tx;
    float ss = 0.f;
    #pragma unroll 16
    for (int c = 0; c < 64; ++c){ float t = px[(size_t)(c*4)*HW]; ss += t*t; }
    red[ty][tx] = ss;
    __syncthreads();
    if (ty == 0){
        float s = red[0][tx]+red[1][tx]+red[2][tx]+red[3][tx];
        invn[n*HW + hw0 + tx] = 1.0f / fmaxf(sqrtf(s), 1e-12f);
    }
}

// ---------------- transpose + normalize + fp16: Lt[n][hw][c] ----------------
__global__ __launch_bounds__(256) void k_transpose(const float* __restrict__ x,
                                                   const float* __restrict__ invn,
                                                   _Float16* __restrict__ Lt){
    __shared__ float tile[64][65];
    int n   = blockIdx.z;
    int hw0 = blockIdx.x * 64;
    int c0  = blockIdx.y * 64;
    int tx = threadIdx.x & 63, ty = threadIdx.x >> 6;
    float inv = invn[n*HW + hw0 + tx];
    const float* px = x + ((size_t)(n*C_DIM + c0))*HW + hw0 + tx;
    #pragma unroll
    for (int r = 0; r < 16; ++r){
        int cl = ty + r*4;
        tile[cl][tx] = px[(size_t)cl*HW] * inv;
    }
    __syncthreads();
    #pragma unroll
    for (int r = 0; r < 16; ++r){
        int hwl = ty + r*4;
        Lt[((size_t)(n*HW + hw0 + hwl))*C_DIM + c0 + tx] = (_Float16)tile[tx][hwl];
    }
}

// ---------------- gather anchors from Lt (coalesced): sxT[n][j][c] fp16 ----------------
__global__ __launch_bounds__(256) void k_gather(const _Float16* __restrict__ Lt,
                                                const int* __restrict__ sidx,
                                                _Float16* __restrict__ sxT){
    int n  = blockIdx.y;
    int jj = blockIdx.x*8 + (threadIdx.x >> 5);
    int c8 = (threadIdx.x & 31) * 8;
    int p  = sidx[jj];
    *(f16x8*)&sxT[((size_t)(n*K_A + jj))*C_DIM + c8] =
        *(const f16x8*)&Lt[((size_t)(n*HW + p))*C_DIM + c8];
}

// ======== GEMM1: A0[n*HW+hw][j] = exp(score/T) ========
// 128x128 tile, BK=64, global_load_lds w/ XOR-swizzled source, swizzled ds_read.
__global__ __launch_bounds__(256) void k_gemm1(const _Float16* __restrict__ Lt,
                                               const _Float16* __restrict__ sxT,
                                               _Float16* __restrict__ A0){
    __shared__ _Float16 As[128*64];
    __shared__ _Float16 Bs[128*64];
    const int nb = blockIdx.z;
    const int mbase = blockIdx.x * 128;
    const int jbase = blockIdx.y * 128;
    const int t = threadIdx.x;
    const int lane = t & 63, w = t >> 6;
    const int wm = (w >> 1)*64, wn = (w & 1)*64;
    const int l15 = lane & 15, lq = lane >> 4;

    f32x4 acc[4][4] = {};
    const _Float16* pa = Lt  + ((size_t)(nb*HW  + mbase))*C_DIM;
    const _Float16* pb = sxT + ((size_t)(nb*K_A + jbase))*C_DIM;

    const int srow0  = w*32 + (lane >> 3);   // + q*8
    const int schunk = lane & 7;

    for (int kt = 0; kt < 4; ++kt){
        int k0 = kt*64;
        #pragma unroll
        for (int q = 0; q < 4; ++q){
            int row = srow0 + q*8;
            int cs = (schunk ^ (row & 7)) << 3;              // swizzled source column (f16 elems)
            gload_lds16(pa + (size_t)row*C_DIM + k0 + cs, &As[(w*32 + q*8)*64]);
            gload_lds16(pb + (size_t)row*C_DIM + k0 + cs, &Bs[(w*32 + q*8)*64]);
        }
        __syncthreads();
        #pragma unroll
        for (int kk = 0; kk < 2; ++kk){
            f16x8 af[4], bf[4];
            #pragma unroll
            for (int mi = 0; mi < 4; ++mi){
                int r = wm + mi*16 + l15, c = kk*4 + lq;
                af[mi] = *(const f16x8*)&As[r*64 + ((c ^ (r & 7)) << 3)];
            }
            #pragma unroll
            for (int ni = 0; ni < 4; ++ni){
                int r = wn + ni*16 + l15, c = kk*4 + lq;
                bf[ni] = *(const f16x8*)&Bs[r*64 + ((c ^ (r & 7)) << 3)];
            }
            #pragma unroll
            for (int mi = 0; mi < 4; ++mi)
                #pragma unroll
                for (int ni = 0; ni < 4; ++ni)
                    acc[mi][ni] = __builtin_amdgcn_mfma_f32_16x16x32_f16(af[mi], bf[ni], acc[mi][ni], 0, 0, 0);
        }
        __syncthreads();
    }
    #pragma unroll
    for (int mi = 0; mi < 4; ++mi)
        #pragma unroll
        for (int ni = 0; ni < 4; ++ni)
            #pragma unroll
            for (int r = 0; r < 4; ++r){
                int hw = mbase + wm + mi*16 + lq*4 + r;
                int j  = jbase + wn + ni*16 + l15;
                float e = __expf(acc[mi][ni][r] * TEMP_INV);
                A0[((size_t)(nb*HW + hw))*K_A + j] = (_Float16)e;
            }
}

// ---------------- Sinkhorn column pass: part[b][j] = sum_{i in chunk} A0[i][j]*u[i] ----------------
__global__ __launch_bounds__(256) void k_colpass(const _Float16* __restrict__ A0,
                                                 const float* __restrict__ u,
                                                 float* __restrict__ part){
    __shared__ float red[4][512];
    int b = blockIdx.x;
    int tg = threadIdx.x >> 6, lane = threadIdx.x & 63;
    float acc[8] = {};
    for (int it = 0; it < 32; ++it){
        int i = (b << 7) + (it << 2) + tg;
        f16x8 a = *(const f16x8*)&A0[(size_t)i*K_A + (lane << 3)];
        float ui = u[i];
        #pragma unroll
        for (int e = 0; e < 8; ++e) acc[e] += (float)a[e] * ui;
    }
    #pragma unroll
    for (int e = 0; e < 8; ++e) red[tg][(lane<<3)+e] = acc[e];
    __syncthreads();
    if (tg == 0){
        #pragma unroll
        for (int e = 0; e < 8; ++e){
            int j = (lane<<3)+e;
            part[((size_t)b << 9) + j] = red[0][j]+red[1][j]+red[2][j]+red[3][j];
        }
    }
}

// v[j] <- 128 * v[j] / max(v[j]*S_j, EPS)
__global__ __launch_bounds__(64) void k_colfinish(const float* __restrict__ part, float* __restrict__ v){
    int j = blockIdx.x;
    int lane = threadIdx.x;
    float s = 0.f;
    #pragma unroll
    for (int e = 0; e < 8; ++e) s += part[((size_t)(lane + e*64) << 9) + j];
    #pragma unroll
    for (int off = 32; off; off >>= 1) s += __shfl_xor(s, off);
    if (lane == 0){
        float vo = v[j];
        v[j] = 128.0f * vo / fmaxf(vo * s, EPS_SK);
    }
}

// ---------------- FUSED: row-update u (from v) + next column partials (one A0 read) ----------------
__global__ __launch_bounds__(256) void k_fused(const _Float16* __restrict__ A0,
                                               const float* __restrict__ v,
                                               float* __restrict__ u,
                                               float* __restrict__ part){
    __shared__ float red[4][512];
    int b = blockIdx.x;
    int tg = threadIdx.x >> 6, lane = threadIdx.x & 63;
    float vr[8];
    const float* pv = v + (lane << 3);
    #pragma unroll
    for (int e = 0; e < 8; ++e) vr[e] = pv[e];
    float acc[8] = {};
    for (int it = 0; it < 32; ++it){
        int i = (b << 7) + (it << 2) + tg;
        f16x8 a = *(const f16x8*)&A0[(size_t)i*K_A + (lane << 3)];
        float r = 0.f;
        #pragma unroll
        for (int e = 0; e < 8; ++e) r += (float)a[e] * vr[e];
        #pragma unroll
        for (int off = 32; off; off >>= 1) r += __shfl_xor(r, off);   // all lanes hold total
        float uo = u[i];                                              // broadcast load
        float un = uo / fmaxf(uo * r, EPS_SK);
        if (lane == 0) u[i] = un;
        #pragma unroll
        for (int e = 0; e < 8; ++e) acc[e] += (float)a[e] * un;
    }
    #pragma unroll
    for (int e = 0; e < 8; ++e) red[tg][(lane<<3)+e] = acc[e];
    __syncthreads();
    if (tg == 0){
        #pragma unroll
        for (int e = 0; e < 8; ++e){
            int j = (lane<<3)+e;
            part[((size_t)b << 9) + j] = red[0][j]+red[1][j]+red[2][j]+red[3][j];
        }
    }
}

// ---------------- final row pass: u <- u/max(u*(A0 v), EPS) ----------------
__global__ __launch_bounds__(256) void k_rowpass(const _Float16* __restrict__ A0,
                                                 const float* __restrict__ v,
                                                 float* __restrict__ u){
    int wv   = (blockIdx.x << 2) + (threadIdx.x >> 6);
    int lane = threadIdx.x & 63;
    float vr[8];
    const float* pv = v + (lane << 3);
    #pragma unroll
    for (int e = 0; e < 8; ++e) vr[e] = pv[e];
    int i0 = wv << 4;
    for (int rr = 0; rr < 16; ++rr){
        int i = i0 + rr;
        f16x8 a = *(const f16x8*)&A0[(size_t)i*K_A + (lane << 3)];
        float r = 0.f;
        #pragma unroll
        for (int e = 0; e < 8; ++e) r += (float)a[e] * vr[e];
        #pragma unroll
        for (int off = 32; off; off >>= 1) r += __shfl_xor(r, off);
        if (lane == 0){
            float uo = u[i];
            u[i] = uo / fmaxf(uo * r, EPS_SK);
        }
    }
}

// ---------------- SXv[n][c][j] = sxT[n][j][c] * v[j]  (LDS transpose, fp16) ----------------
__global__ __launch_bounds__(256) void k_sxvT(const _Float16* __restrict__ sxT,
                                              const float* __restrict__ v,
                                              _Float16* __restrict__ SXv){
    __shared__ float tl[64][65];
    int n  = blockIdx.z;
    int j0 = blockIdx.x * 64;
    int c0 = blockIdx.y * 64;
    int tx = threadIdx.x & 63, ty = threadIdx.x >> 6;
    #pragma unroll
    for (int r = 0; r < 16; ++r){
        int jl = ty + r*4;
        tl[jl][tx] = (float)sxT[((size_t)(n*K_A + j0 + jl))*C_DIM + c0 + tx] * v[j0 + jl];
    }
    __syncthreads();
    #pragma unroll
    for (int r = 0; r < 16; ++r){
        int cl = ty + r*4;
        SXv[((size_t)(n*C_DIM + c0 + cl))*K_A + j0 + tx] = (_Float16)tl[tx][cl];
    }
}

// ======== GEMM2: out[n][c][hw] = u[hw] * sum_j SXv[c][j]*A0[hw][j] ========
__global__ __launch_bounds__(256) void k_gemm2(const _Float16* __restrict__ SXv,
                                               const _Float16* __restrict__ A0,
                                               const float* __restrict__ u,
                                               float* __restrict__ out){
    __shared__ _Float16 As[128*64];
    __shared__ _Float16 Bs[128*64];
    const int nb = blockIdx.z;
    const int mbase = blockIdx.x * 128;   // c
    const int nbase = blockIdx.y * 128;   // hw
    const int t = threadIdx.x;
    const int lane = t & 63, w = t >> 6;
    const int wm = (w >> 1)*64, wn = (w & 1)*64;
    const int l15 = lane & 15, lq = lane >> 4;

    f32x4 acc[4][4] = {};
    const _Float16* pa = SXv + ((size_t)(nb*C_DIM + mbase))*K_A;
    const _Float16* pb = A0  + ((size_t)(nb*HW   + nbase))*K_A;

    const int srow0  = w*32 + (lane >> 3);
    const int schunk = lane & 7;

    for (int kt = 0; kt < 8; ++kt){
        int k0 = kt*64;
        #pragma unroll
        for (int q = 0; q < 4; ++q){
            int row = srow0 + q*8;
            int cs = (schunk ^ (row & 7)) << 3;
            gload_lds16(pa + (size_t)row*K_A + k0 + cs, &As[(w*32 + q*8)*64]);
            gload_lds16(pb + (size_t)row*K_A + k0 + cs, &Bs[(w*32 + q*8)*64]);
        }
        __syncthreads();
        #pragma unroll
        for (int kk = 0; kk < 2; ++kk){
            f16x8 af[4], bf[4];
            #pragma unroll
            for (int mi = 0; mi < 4; ++mi){
                int r = wm + mi*16 + l15, c = kk*4 + lq;
                af[mi] = *(const f16x8*)&As[r*64 + ((c ^ (r & 7)) << 3)];
            }
            #pragma unroll
            for (int ni = 0; ni < 4; ++ni){
                int r = wn + ni*16 + l15, c = kk*4 + lq;
                bf[ni] = *(const f16x8*)&Bs[r*64 + ((c ^ (r & 7)) << 3)];
            }
            #pragma unroll
            for (int mi = 0; mi < 4; ++mi)
                #pragma unroll
                for (int ni = 0; ni < 4; ++ni)
                    acc[mi][ni] = __builtin_amdgcn_mfma_f32_16x16x32_f16(af[mi], bf[ni], acc[mi][ni], 0, 0, 0);
        }
        __syncthreads();
    }
    #pragma unroll
    for (int mi = 0; mi < 4; ++mi)
        #pragma unroll
        for (int ni = 0; ni < 4; ++ni)
            #pragma unroll
            for (int r = 0; r < 4; ++r){
                int c  = mbase + wm + mi*16 + lq*4 + r;
                int hw = nbase + wn + ni*16 + l15;
                float val = acc[mi][ni][r] * u[nb*HW + hw];
                out[((size_t)(nb*C_DIM + c))*HW + hw] = val;
            }
}

extern "C" void kernel_launch(void* const* d_in, const int* in_sizes, int n_in,
                              void* d_out, int out_size, void* d_ws, size_t ws_size,
                              hipStream_t stream){
    const float* x  = (const float*)d_in[0];
    const int* sidx = (const int*)d_in[1];
    float* out = (float*)d_out;

    char* ws = (char*)d_ws;
    _Float16* Lt  = (_Float16*)ws;  ws += (size_t)N_B*HW*C_DIM*2;      // 32 MiB
    _Float16* A0  = (_Float16*)ws;  ws += (size_t)M_TOT*K_A*2;         // 64 MiB
    _Float16* sxT = (_Float16*)ws;  ws += (size_t)N_B*K_A*C_DIM*2;     // 4 MiB
    _Float16* SXv = (_Float16*)ws;  ws += (size_t)N_B*C_DIM*K_A*2;     // 4 MiB
    float*    invn= (float*)ws;     ws += (size_t)M_TOT*4;
    float*    u   = (float*)ws;     ws += (size_t)M_TOT*4;
    float*    v   = (float*)ws;     ws += (size_t)K_A*4;
    float*    part= (float*)ws;     ws += (size_t)512*K_A*4;           // 1 MiB

    k_init     <<<256, 256, 0, stream>>>(u, v);
    k_norm     <<<1024, 256, 0, stream>>>(x, invn);
    k_transpose<<<dim3(64,4,16), 256, 0, stream>>>(x, invn, Lt);
    k_gather   <<<dim3(64,16), 256, 0, stream>>>(Lt, sidx, sxT);
    k_gemm1    <<<dim3(32,4,16), 256, 0, stream>>>(Lt, sxT, A0);

    // Sinkhorn: col(S1) -> v1; [fused: u_t + S_{t+1}] x3 with colfinish; final rowpass -> u4
    k_colpass  <<<512, 256, 0, stream>>>(A0, u, part);
    k_colfinish<<<512, 64, 0, stream>>>(part, v);
    for (int it = 0; it < 3; ++it){
        k_fused    <<<512, 256, 0, stream>>>(A0, v, u, part);
        k_colfinish<<<512, 64, 0, stream>>>(part, v);
    }
    k_rowpass<<<1024, 256, 0, stream>>>(A0, v, u);

    k_sxvT <<<dim3(8,4,16), 256, 0, stream>>>(sxT, v, SXv);
    k_gemm2<<<dim3(2,32,16), 256, 0, stream>>>(SXv, A0, u, out);
}

// Round 4
// 176.639 us; speedup vs baseline: 1.9937x; 1.2292x over previous
//
#include <hip/hip_runtime.h>
#include <hip/hip_bf16.h>
#include <hip/hip_fp16.h>

#define N_B 16
#define C_DIM 256
#define HW 4096
#define M_TOT (N_B*HW)          // 65536 global rows
#define K_A 512
#define TEMP_INV (1.0f/0.3f)
#define EPS_SK 1e-12f

typedef _Float16 f16x8 __attribute__((ext_vector_type(8)));
typedef _Float16 f16x4 __attribute__((ext_vector_type(4)));
typedef float f32x4 __attribute__((ext_vector_type(4)));

#define GLOBAL_AS __attribute__((address_space(1)))
#define LDS_AS __attribute__((address_space(3)))
__device__ __forceinline__ void gload_lds16(const void* g, void* l){
    __builtin_amdgcn_global_load_lds((GLOBAL_AS const void*)g, (LDS_AS void*)l, 16, 0, 0);
}

// ---------------- init u=1, v=1 ----------------
__global__ __launch_bounds__(256) void k_init(float* u, float* v){
    int i = blockIdx.x*256 + threadIdx.x;
    if (i < M_TOT) u[i] = 1.0f;
    if (i < K_A)   v[i] = 1.0f;
}

// ---------------- fused: read x once -> channel L2 norm -> Lt[n][hw][c] fp16 ----------------
__global__ __launch_bounds__(256) void k_normtrans(const float* __restrict__ x,
                                                   _Float16* __restrict__ Lt){
    __shared__ float tl[64][257];   // [hw][c], pad 257 to break bank patterns
    __shared__ float red[4][64];
    __shared__ float invs[64];
    int n   = blockIdx.x >> 6;
    int hw0 = (blockIdx.x & 63) * 64;
    int tx4 = threadIdx.x & 15;          // hw quad (float4)
    int cy  = threadIdx.x >> 4;          // c row group (16 rows per iter)
    const float* px = x + ((size_t)(n*C_DIM + cy))*HW + hw0 + tx4*4;
    #pragma unroll
    for (int r = 0; r < 16; ++r){
        float4 xv = *(const float4*)(px + (size_t)(r*16)*HW);
        int c = cy + r*16;
        tl[tx4*4+0][c] = xv.x;
        tl[tx4*4+1][c] = xv.y;
        tl[tx4*4+2][c] = xv.z;
        tl[tx4*4+3][c] = xv.w;
    }
    __syncthreads();
    int tx = threadIdx.x & 63, ty = threadIdx.x >> 6;
    float ss = 0.f;
    #pragma unroll
    for (int cc = 0; cc < 64; ++cc){
        float tv = tl[tx][cc*4 + ty];
        ss += tv*tv;
    }
    red[ty][tx] = ss;
    __syncthreads();
    if (ty == 0){
        float s = red[0][tx]+red[1][tx]+red[2][tx]+red[3][tx];
        invs[tx] = 1.0f / fmaxf(sqrtf(s), 1e-12f);
    }
    __syncthreads();
    #pragma unroll
    for (int r = 0; r < 16; ++r){
        int hwl = ty + r*4;
        float inv = invs[hwl];
        float4 a = *(const float4*)&tl[hwl][tx*4];
        f16x4 h;
        h[0] = (_Float16)(a.x*inv); h[1] = (_Float16)(a.y*inv);
        h[2] = (_Float16)(a.z*inv); h[3] = (_Float16)(a.w*inv);
        *(f16x4*)&Lt[((size_t)(n*HW + hw0 + hwl))*C_DIM + tx*4] = h;
    }
}

// ---------------- gather anchors from Lt (coalesced): sxT[n][j][c] fp16 ----------------
__global__ __launch_bounds__(256) void k_gather(const _Float16* __restrict__ Lt,
                                                const int* __restrict__ sidx,
                                                _Float16* __restrict__ sxT){
    int n  = blockIdx.y;
    int jj = blockIdx.x*8 + (threadIdx.x >> 5);
    int c8 = (threadIdx.x & 31) * 8;
    int p  = sidx[jj];
    *(f16x8*)&sxT[((size_t)(n*K_A + jj))*C_DIM + c8] =
        *(const f16x8*)&Lt[((size_t)(n*HW + p))*C_DIM + c8];
}

// ======== GEMM1 + first Sinkhorn column partials ========
// A0[n*HW+hw][j] = exp(score/T); part[chunk][j] = per-128-row colsum (u0 = 1)
__global__ __launch_bounds__(256) void k_gemm1(const _Float16* __restrict__ Lt,
                                               const _Float16* __restrict__ sxT,
                                               _Float16* __restrict__ A0,
                                               float* __restrict__ part){
    __shared__ _Float16 As[128*64];
    __shared__ _Float16 Bs[128*64];
    __shared__ float colred[4][128];
    const int nb = blockIdx.z;
    const int mbase = blockIdx.x * 128;
    const int jbase = blockIdx.y * 128;
    const int t = threadIdx.x;
    const int lane = t & 63, w = t >> 6;
    const int wm = (w >> 1)*64, wn = (w & 1)*64;
    const int l15 = lane & 15, lq = lane >> 4;

    f32x4 acc[4][4] = {};
    const _Float16* pa = Lt  + ((size_t)(nb*HW  + mbase))*C_DIM;
    const _Float16* pb = sxT + ((size_t)(nb*K_A + jbase))*C_DIM;

    const int srow0  = w*32 + (lane >> 3);
    const int schunk = lane & 7;

    for (int kt = 0; kt < 4; ++kt){
        int k0 = kt*64;
        #pragma unroll
        for (int q = 0; q < 4; ++q){
            int row = srow0 + q*8;
            int cs = (schunk ^ (row & 7)) << 3;
            gload_lds16(pa + (size_t)row*C_DIM + k0 + cs, &As[(w*32 + q*8)*64]);
            gload_lds16(pb + (size_t)row*C_DIM + k0 + cs, &Bs[(w*32 + q*8)*64]);
        }
        __syncthreads();
        #pragma unroll
        for (int kk = 0; kk < 2; ++kk){
            f16x8 af[4], bf[4];
            #pragma unroll
            for (int mi = 0; mi < 4; ++mi){
                int r = wm + mi*16 + l15, c = kk*4 + lq;
                af[mi] = *(const f16x8*)&As[r*64 + ((c ^ (r & 7)) << 3)];
            }
            #pragma unroll
            for (int ni = 0; ni < 4; ++ni){
                int r = wn + ni*16 + l15, c = kk*4 + lq;
                bf[ni] = *(const f16x8*)&Bs[r*64 + ((c ^ (r & 7)) << 3)];
            }
            #pragma unroll
            for (int mi = 0; mi < 4; ++mi)
                #pragma unroll
                for (int ni = 0; ni < 4; ++ni)
                    acc[mi][ni] = __builtin_amdgcn_mfma_f32_16x16x32_f16(af[mi], bf[ni], acc[mi][ni], 0, 0, 0);
        }
        __syncthreads();
    }
    float csum[4] = {0.f, 0.f, 0.f, 0.f};
    #pragma unroll
    for (int mi = 0; mi < 4; ++mi)
        #pragma unroll
        for (int ni = 0; ni < 4; ++ni)
            #pragma unroll
            for (int r = 0; r < 4; ++r){
                int hw = mbase + wm + mi*16 + lq*4 + r;
                int j  = jbase + wn + ni*16 + l15;
                float e = __expf(acc[mi][ni][r] * TEMP_INV);
                A0[((size_t)(nb*HW + hw))*K_A + j] = (_Float16)e;
                csum[ni] += e;
            }
    #pragma unroll
    for (int ni = 0; ni < 4; ++ni){
        float cv = csum[ni];
        cv += __shfl_xor(cv, 16);
        cv += __shfl_xor(cv, 32);
        if (lane < 16) colred[w][wn + ni*16 + l15] = cv;
    }
    __syncthreads();
    if (t < 128){
        int jj = t;
        float s = (jj < 64) ? (colred[0][jj] + colred[2][jj])
                            : (colred[1][jj] + colred[3][jj]);
        part[((size_t)(nb*32 + blockIdx.x))*K_A + jbase + jj] = s;
    }
}

// v[j] <- 128 * v[j] / max(v[j]*S_j, EPS); S_j summed over nchunks partials
__global__ __launch_bounds__(64) void k_colfinish(const float* __restrict__ part,
                                                  float* __restrict__ v, int nchunks){
    int j = blockIdx.x;
    int lane = threadIdx.x;
    float s = 0.f;
    for (int r = lane; r < nchunks; r += 64) s += part[(size_t)r*K_A + j];
    #pragma unroll
    for (int off = 32; off; off >>= 1) s += __shfl_xor(s, off);
    if (lane == 0){
        float vo = v[j];
        v[j] = 128.0f * vo / fmaxf(vo * s, EPS_SK);
    }
}

// ---------------- FUSED: row-update u (from v) + next column partials (one A0 read) ----------------
__global__ __launch_bounds__(256) void k_fused(const _Float16* __restrict__ A0,
                                               const float* __restrict__ v,
                                               float* __restrict__ u,
                                               float* __restrict__ part){
    __shared__ float red[4][512];
    int b = blockIdx.x;                         // 1024 blocks, 64 rows each
    int tg = threadIdx.x >> 6, lane = threadIdx.x & 63;
    float vr[8];
    const float* pv = v + (lane << 3);
    #pragma unroll
    for (int e = 0; e < 8; ++e) vr[e] = pv[e];
    float acc[8] = {};
    for (int it = 0; it < 16; ++it){
        int i = (b << 6) + (it << 2) + tg;
        f16x8 a = *(const f16x8*)&A0[(size_t)i*K_A + (lane << 3)];
        float r = 0.f;
        #pragma unroll
        for (int e = 0; e < 8; ++e) r += (float)a[e] * vr[e];
        #pragma unroll
        for (int off = 32; off; off >>= 1) r += __shfl_xor(r, off);
        float uo = u[i];
        float un = uo / fmaxf(uo * r, EPS_SK);
        if (lane == 0) u[i] = un;
        #pragma unroll
        for (int e = 0; e < 8; ++e) acc[e] += (float)a[e] * un;
    }
    #pragma unroll
    for (int e = 0; e < 8; ++e) red[tg][(lane<<3)+e] = acc[e];
    __syncthreads();
    if (tg == 0){
        #pragma unroll
        for (int e = 0; e < 8; ++e){
            int j = (lane<<3)+e;
            part[((size_t)b)*K_A + j] = red[0][j]+red[1][j]+red[2][j]+red[3][j];
        }
    }
}

// ---------------- SXv[n][c][j] = sxT[n][j][c] * v[j]  (LDS transpose, fp16) ----------------
__global__ __launch_bounds__(256) void k_sxvT(const _Float16* __restrict__ sxT,
                                              const float* __restrict__ v,
                                              _Float16* __restrict__ SXv){
    __shared__ float tl[64][65];
    int n  = blockIdx.z;
    int j0 = blockIdx.x * 64;
    int c0 = blockIdx.y * 64;
    int tx = threadIdx.x & 63, ty = threadIdx.x >> 6;
    #pragma unroll
    for (int r = 0; r < 16; ++r){
        int jl = ty + r*4;
        tl[jl][tx] = (float)sxT[((size_t)(n*K_A + j0 + jl))*C_DIM + c0 + tx] * v[j0 + jl];
    }
    __syncthreads();
    #pragma unroll
    for (int r = 0; r < 16; ++r){
        int cl = ty + r*4;
        SXv[((size_t)(n*C_DIM + c0 + cl))*K_A + j0 + tx] = (_Float16)tl[tx][cl];
    }
}

// ======== GEMM2 + final row-normalize ========
// out[n][c][hw] = u4[hw] * sum_j SXv[c][j]*A0[hw][j];  u4 = u3/max(u3*R), R = A0 . v4
__global__ __launch_bounds__(256) void k_gemm2(const _Float16* __restrict__ SXv,
                                               const _Float16* __restrict__ A0,
                                               const float* __restrict__ v,
                                               const float* __restrict__ u,
                                               float* __restrict__ out){
    __shared__ _Float16 As[128*64];
    __shared__ _Float16 Bs[128*64];
    __shared__ float vs[512];
    const int nb = blockIdx.z;
    const int mbase = blockIdx.x * 128;   // c
    const int nbase = blockIdx.y * 128;   // hw
    const int t = threadIdx.x;
    const int lane = t & 63, w = t >> 6;
    const int wm = (w >> 1)*64, wn = (w & 1)*64;
    const int l15 = lane & 15, lq = lane >> 4;

    vs[t] = v[t];
    vs[t + 256] = v[t + 256];

    f32x4 acc[4][4] = {};
    float rf[4] = {0.f, 0.f, 0.f, 0.f};
    const _Float16* pa = SXv + ((size_t)(nb*C_DIM + mbase))*K_A;
    const _Float16* pb = A0  + ((size_t)(nb*HW   + nbase))*K_A;

    const int srow0  = w*32 + (lane >> 3);
    const int schunk = lane & 7;

    for (int kt = 0; kt < 8; ++kt){
        int k0 = kt*64;
        #pragma unroll
        for (int q = 0; q < 4; ++q){
            int row = srow0 + q*8;
            int cs = (schunk ^ (row & 7)) << 3;
            gload_lds16(pa + (size_t)row*K_A + k0 + cs, &As[(w*32 + q*8)*64]);
            gload_lds16(pb + (size_t)row*K_A + k0 + cs, &Bs[(w*32 + q*8)*64]);
        }
        __syncthreads();
        #pragma unroll
        for (int kk = 0; kk < 2; ++kk){
            f16x8 af[4], bf[4];
            #pragma unroll
            for (int mi = 0; mi < 4; ++mi){
                int r = wm + mi*16 + l15, c = kk*4 + lq;
                af[mi] = *(const f16x8*)&As[r*64 + ((c ^ (r & 7)) << 3)];
            }
            #pragma unroll
            for (int ni = 0; ni < 4; ++ni){
                int r = wn + ni*16 + l15, c = kk*4 + lq;
                bf[ni] = *(const f16x8*)&Bs[r*64 + ((c ^ (r & 7)) << 3)];
            }
            #pragma unroll
            for (int mi = 0; mi < 4; ++mi)
                #pragma unroll
                for (int ni = 0; ni < 4; ++ni)
                    acc[mi][ni] = __builtin_amdgcn_mfma_f32_16x16x32_f16(af[mi], bf[ni], acc[mi][ni], 0, 0, 0);
            // row-sum accumulation: R += A0[row] . v over this K slice
            float4 v0 = *(const float4*)&vs[k0 + (kk*4 + lq)*8];
            float4 v1 = *(const float4*)&vs[k0 + (kk*4 + lq)*8 + 4];
            #pragma unroll
            for (int ni = 0; ni < 4; ++ni){
                rf[ni] += (float)bf[ni][0]*v0.x + (float)bf[ni][1]*v0.y
                        + (float)bf[ni][2]*v0.z + (float)bf[ni][3]*v0.w
                        + (float)bf[ni][4]*v1.x + (float)bf[ni][5]*v1.y
                        + (float)bf[ni][6]*v1.z + (float)bf[ni][7]*v1.w;
            }
        }
        __syncthreads();
    }
    float un[4];
    #pragma unroll
    for (int ni = 0; ni < 4; ++ni){
        float rv = rf[ni];
        rv += __shfl_xor(rv, 16);
        rv += __shfl_xor(rv, 32);
        float uo = u[nb*HW + nbase + wn + ni*16 + l15];
        un[ni] = uo / fmaxf(uo * rv, EPS_SK);
    }
    #pragma unroll
    for (int mi = 0; mi < 4; ++mi)
        #pragma unroll
        for (int ni = 0; ni < 4; ++ni)
            #pragma unroll
            for (int r = 0; r < 4; ++r){
                int c  = mbase + wm + mi*16 + lq*4 + r;
                int hw = nbase + wn + ni*16 + l15;
                out[((size_t)(nb*C_DIM + c))*HW + hw] = acc[mi][ni][r] * un[ni];
            }
}

extern "C" void kernel_launch(void* const* d_in, const int* in_sizes, int n_in,
                              void* d_out, int out_size, void* d_ws, size_t ws_size,
                              hipStream_t stream){
    const float* x  = (const float*)d_in[0];
    const int* sidx = (const int*)d_in[1];
    float* out = (float*)d_out;

    char* ws = (char*)d_ws;
    _Float16* Lt  = (_Float16*)ws;  ws += (size_t)N_B*HW*C_DIM*2;      // 32 MiB
    _Float16* A0  = (_Float16*)ws;  ws += (size_t)M_TOT*K_A*2;         // 64 MiB
    _Float16* sxT = (_Float16*)ws;  ws += (size_t)N_B*K_A*C_DIM*2;     // 4 MiB
    _Float16* SXv = (_Float16*)ws;  ws += (size_t)N_B*C_DIM*K_A*2;     // 4 MiB
    float*    u   = (float*)ws;     ws += (size_t)M_TOT*4;
    float*    v   = (float*)ws;     ws += (size_t)K_A*4;
    float*    part= (float*)ws;     ws += (size_t)1024*K_A*4;          // 2 MiB

    k_init     <<<256, 256, 0, stream>>>(u, v);
    k_normtrans<<<1024, 256, 0, stream>>>(x, Lt);
    k_gather   <<<dim3(64,16), 256, 0, stream>>>(Lt, sidx, sxT);
    k_gemm1    <<<dim3(32,4,16), 256, 0, stream>>>(Lt, sxT, A0, part);

    // Sinkhorn: v1 from gemm1 partials; 3x (row-update + next col partials); final row fold in gemm2
    k_colfinish<<<512, 64, 0, stream>>>(part, v, 512);
    for (int it = 0; it < 3; ++it){
        k_fused    <<<1024, 256, 0, stream>>>(A0, v, u, part);
        k_colfinish<<<512, 64, 0, stream>>>(part, v, 1024);
    }

    k_sxvT <<<dim3(8,4,16), 256, 0, stream>>>(sxT, v, SXv);
    k_gemm2<<<dim3(2,32,16), 256, 0, stream>>>(SXv, A0, v, u, out);
}

// Round 5
// 174.554 us; speedup vs baseline: 2.0176x; 1.0119x over previous
//
#include <hip/hip_runtime.h>
#include <hip/hip_bf16.h>
#include <hip/hip_fp16.h>

#define N_B 16
#define C_DIM 256
#define HW 4096
#define M_TOT (N_B*HW)          // 65536 global rows
#define K_A 512
#define TEMP_INV (1.0f/0.3f)
#define EPS_SK 1e-12f

typedef _Float16 f16x8 __attribute__((ext_vector_type(8)));
typedef _Float16 f16x4 __attribute__((ext_vector_type(4)));
typedef float f32x4 __attribute__((ext_vector_type(4)));

#define GLOBAL_AS __attribute__((address_space(1)))
#define LDS_AS __attribute__((address_space(3)))
__device__ __forceinline__ void gload_lds16(const void* g, void* l){
    __builtin_amdgcn_global_load_lds((GLOBAL_AS const void*)g, (LDS_AS void*)l, 16, 0, 0);
}

// ---------------- init u=1, v=1 ----------------
__global__ __launch_bounds__(256) void k_init(float* u, float* v){
    int i = blockIdx.x*256 + threadIdx.x;
    if (i < M_TOT) u[i] = 1.0f;
    if (i < K_A)   v[i] = 1.0f;
}

// ---------------- fused: read x once -> channel L2 norm -> Lt[n][hw][c] fp16 ----------------
__global__ __launch_bounds__(256) void k_normtrans(const float* __restrict__ x,
                                                   _Float16* __restrict__ Lt){
    __shared__ float tl[64][257];
    __shared__ float red[4][64];
    __shared__ float invs[64];
    int n   = blockIdx.x >> 6;
    int hw0 = (blockIdx.x & 63) * 64;
    int tx4 = threadIdx.x & 15;
    int cy  = threadIdx.x >> 4;
    const float* px = x + ((size_t)(n*C_DIM + cy))*HW + hw0 + tx4*4;
    #pragma unroll
    for (int r = 0; r < 16; ++r){
        float4 xv = *(const float4*)(px + (size_t)(r*16)*HW);
        int c = cy + r*16;
        tl[tx4*4+0][c] = xv.x;
        tl[tx4*4+1][c] = xv.y;
        tl[tx4*4+2][c] = xv.z;
        tl[tx4*4+3][c] = xv.w;
    }
    __syncthreads();
    int tx = threadIdx.x & 63, ty = threadIdx.x >> 6;
    float ss = 0.f;
    #pragma unroll
    for (int cc = 0; cc < 64; ++cc){
        float tv = tl[tx][cc*4 + ty];
        ss += tv*tv;
    }
    red[ty][tx] = ss;
    __syncthreads();
    if (ty == 0){
        float s = red[0][tx]+red[1][tx]+red[2][tx]+red[3][tx];
        invs[tx] = 1.0f / fmaxf(sqrtf(s), 1e-12f);
    }
    __syncthreads();
    #pragma unroll
    for (int r = 0; r < 16; ++r){
        int hwl = ty + r*4;
        float inv = invs[hwl];
        float4 a = *(const float4*)&tl[hwl][tx*4];
        f16x4 h;
        h[0] = (_Float16)(a.x*inv); h[1] = (_Float16)(a.y*inv);
        h[2] = (_Float16)(a.z*inv); h[3] = (_Float16)(a.w*inv);
        *(f16x4*)&Lt[((size_t)(n*HW + hw0 + hwl))*C_DIM + tx*4] = h;
    }
}

// ---------------- gather anchors from Lt (coalesced): sxT[n][j][c] fp16 ----------------
__global__ __launch_bounds__(256) void k_gather(const _Float16* __restrict__ Lt,
                                                const int* __restrict__ sidx,
                                                _Float16* __restrict__ sxT){
    int n  = blockIdx.y;
    int jj = blockIdx.x*8 + (threadIdx.x >> 5);
    int c8 = (threadIdx.x & 31) * 8;
    int p  = sidx[jj];
    *(f16x8*)&sxT[((size_t)(n*K_A + jj))*C_DIM + c8] =
        *(const f16x8*)&Lt[((size_t)(n*HW + p))*C_DIM + c8];
}

// ======== GEMM1 + first Sinkhorn column partials ========
// 128x128 tile, BK=32, double-buffered LDS, 2-phase prefetch (T3-min).
// LDS swizzle: chunk ^= (row>>1)&3 on both stage-source and ds_read (<=2-way, free).
__global__ __launch_bounds__(256) void k_gemm1(const _Float16* __restrict__ Lt,
                                               const _Float16* __restrict__ sxT,
                                               _Float16* __restrict__ A0,
                                               float* __restrict__ part){
    __shared__ _Float16 As[2*128*32];
    __shared__ _Float16 Bs[2*128*32];
    __shared__ float colred[4][128];
    const int nb = blockIdx.z;
    const int mbase = blockIdx.x * 128;
    const int jbase = blockIdx.y * 128;
    const int t = threadIdx.x;
    const int lane = t & 63, w = t >> 6;
    const int wm = (w >> 1)*64, wn = (w & 1)*64;
    const int l15 = lane & 15, lq = lane >> 4;

    f32x4 acc[4][4] = {};
    const _Float16* pa = Lt  + ((size_t)(nb*HW  + mbase))*C_DIM;
    const _Float16* pb = sxT + ((size_t)(nb*K_A + jbase))*C_DIM;

    // stage geometry: 512 chunks (128 rows x 4 chunks of 16B) per matrix, 2 per thread
    const int r0 = t >> 2, ch = t & 3;
    const int r1 = r0 + 64;
    const int cs0 = (ch ^ ((r0 >> 1) & 3)) << 3;
    const int cs1 = (ch ^ ((r1 >> 1) & 3)) << 3;

#define STAGE1(buf, kt) { int k0 = (kt)*32; \
    gload_lds16(pa + (size_t)r0*C_DIM + k0 + cs0, &As[(buf)*4096 + t*8]); \
    gload_lds16(pa + (size_t)r1*C_DIM + k0 + cs1, &As[(buf)*4096 + (256+t)*8]); \
    gload_lds16(pb + (size_t)r0*C_DIM + k0 + cs0, &Bs[(buf)*4096 + t*8]); \
    gload_lds16(pb + (size_t)r1*C_DIM + k0 + cs1, &Bs[(buf)*4096 + (256+t)*8]); }

    STAGE1(0, 0);
    __syncthreads();
    int cur = 0;
    for (int kt = 0; kt < 8; ++kt){
        if (kt < 7) STAGE1(cur^1, kt+1);
        f16x8 af[4], bf[4];
        #pragma unroll
        for (int mi = 0; mi < 4; ++mi){
            int r = wm + mi*16 + l15;
            af[mi] = *(const f16x8*)&As[cur*4096 + r*32 + ((lq ^ ((r>>1)&3)) << 3)];
        }
        #pragma unroll
        for (int ni = 0; ni < 4; ++ni){
            int r = wn + ni*16 + l15;
            bf[ni] = *(const f16x8*)&Bs[cur*4096 + r*32 + ((lq ^ ((r>>1)&3)) << 3)];
        }
        #pragma unroll
        for (int mi = 0; mi < 4; ++mi)
            #pragma unroll
            for (int ni = 0; ni < 4; ++ni)
                acc[mi][ni] = __builtin_amdgcn_mfma_f32_16x16x32_f16(af[mi], bf[ni], acc[mi][ni], 0, 0, 0);
        __syncthreads();
        cur ^= 1;
    }
    float csum[4] = {0.f, 0.f, 0.f, 0.f};
    #pragma unroll
    for (int mi = 0; mi < 4; ++mi)
        #pragma unroll
        for (int ni = 0; ni < 4; ++ni)
            #pragma unroll
            for (int r = 0; r < 4; ++r){
                int hw = mbase + wm + mi*16 + lq*4 + r;
                int j  = jbase + wn + ni*16 + l15;
                float e = __expf(acc[mi][ni][r] * TEMP_INV);
                A0[((size_t)(nb*HW + hw))*K_A + j] = (_Float16)e;
                csum[ni] += e;
            }
    #pragma unroll
    for (int ni = 0; ni < 4; ++ni){
        float cv = csum[ni];
        cv += __shfl_xor(cv, 16);
        cv += __shfl_xor(cv, 32);
        if (lane < 16) colred[w][wn + ni*16 + l15] = cv;
    }
    __syncthreads();
    if (t < 128){
        int jj = t;
        float s = (jj < 64) ? (colred[0][jj] + colred[2][jj])
                            : (colred[1][jj] + colred[3][jj]);
        part[((size_t)(nb*32 + blockIdx.x))*K_A + jbase + jj] = s;
    }
}

// v[j] <- 128 * v[j] / max(v[j]*S_j, EPS); S_j summed over nchunks partials
__global__ __launch_bounds__(64) void k_colfinish(const float* __restrict__ part,
                                                  float* __restrict__ v, int nchunks){
    int j = blockIdx.x;
    int lane = threadIdx.x;
    float s = 0.f;
    for (int r = lane; r < nchunks; r += 64) s += part[(size_t)r*K_A + j];
    #pragma unroll
    for (int off = 32; off; off >>= 1) s += __shfl_xor(s, off);
    if (lane == 0){
        float vo = v[j];
        v[j] = 128.0f * vo / fmaxf(vo * s, EPS_SK);
    }
}

// ---------------- FUSED: row-update u (from v) + next column partials (one A0 read) ----------------
__global__ __launch_bounds__(256) void k_fused(const _Float16* __restrict__ A0,
                                               const float* __restrict__ v,
                                               float* __restrict__ u,
                                               float* __restrict__ part){
    __shared__ float red[4][512];
    int b = blockIdx.x;                         // 1024 blocks, 64 rows each
    int tg = threadIdx.x >> 6, lane = threadIdx.x & 63;
    float vr[8];
    const float* pv = v + (lane << 3);
    #pragma unroll
    for (int e = 0; e < 8; ++e) vr[e] = pv[e];
    float acc[8] = {};
    for (int it = 0; it < 16; ++it){
        int i = (b << 6) + (it << 2) + tg;
        f16x8 a = *(const f16x8*)&A0[(size_t)i*K_A + (lane << 3)];
        float r = 0.f;
        #pragma unroll
        for (int e = 0; e < 8; ++e) r += (float)a[e] * vr[e];
        #pragma unroll
        for (int off = 32; off; off >>= 1) r += __shfl_xor(r, off);
        float uo = u[i];
        float un = uo / fmaxf(uo * r, EPS_SK);
        if (lane == 0) u[i] = un;
        #pragma unroll
        for (int e = 0; e < 8; ++e) acc[e] += (float)a[e] * un;
    }
    #pragma unroll
    for (int e = 0; e < 8; ++e) red[tg][(lane<<3)+e] = acc[e];
    __syncthreads();
    if (tg == 0){
        #pragma unroll
        for (int e = 0; e < 8; ++e){
            int j = (lane<<3)+e;
            part[((size_t)b)*K_A + j] = red[0][j]+red[1][j]+red[2][j]+red[3][j];
        }
    }
}

// ---------------- SXv[n][c][j] = sxT[n][j][c] * v[j]  (LDS transpose, fp16) ----------------
__global__ __launch_bounds__(256) void k_sxvT(const _Float16* __restrict__ sxT,
                                              const float* __restrict__ v,
                                              _Float16* __restrict__ SXv){
    __shared__ float tl[64][65];
    int n  = blockIdx.z;
    int j0 = blockIdx.x * 64;
    int c0 = blockIdx.y * 64;
    int tx = threadIdx.x & 63, ty = threadIdx.x >> 6;
    #pragma unroll
    for (int r = 0; r < 16; ++r){
        int jl = ty + r*4;
        tl[jl][tx] = (float)sxT[((size_t)(n*K_A + j0 + jl))*C_DIM + c0 + tx] * v[j0 + jl];
    }
    __syncthreads();
    #pragma unroll
    for (int r = 0; r < 16; ++r){
        int cl = ty + r*4;
        SXv[((size_t)(n*C_DIM + c0 + cl))*K_A + j0 + tx] = (_Float16)tl[tx][cl];
    }
}

// ======== GEMM2 + final row-normalize ========
// out[n][c][hw] = u4[hw]*sum_j SXv[c][j]*A0[hw][j];  u4 = u3/max(u3*R), R = A0.v via MFMA
// (v-broadcast A-fragment: every lane's A-frag = v[k] -> all D rows equal R[hw], no shfl)
__global__ __launch_bounds__(256) void k_gemm2(const _Float16* __restrict__ SXv,
                                               const _Float16* __restrict__ A0,
                                               const float* __restrict__ v,
                                               const float* __restrict__ u,
                                               float* __restrict__ out){
    __shared__ _Float16 As[2*128*32];
    __shared__ _Float16 Bs[2*128*32];
    __shared__ _Float16 vsh[512];
    const int nb = blockIdx.z;
    const int mbase = blockIdx.x * 128;   // c
    const int nbase = blockIdx.y * 128;   // hw
    const int t = threadIdx.x;
    const int lane = t & 63, w = t >> 6;
    const int wm = (w >> 1)*64, wn = (w & 1)*64;
    const int l15 = lane & 15, lq = lane >> 4;

    vsh[t]       = (_Float16)v[t];
    vsh[t + 256] = (_Float16)v[t + 256];

    f32x4 acc[4][4] = {};
    f32x4 racc[4] = {};
    const _Float16* pa = SXv + ((size_t)(nb*C_DIM + mbase))*K_A;
    const _Float16* pb = A0  + ((size_t)(nb*HW   + nbase))*K_A;

    const int r0 = t >> 2, ch = t & 3;
    const int r1 = r0 + 64;
    const int cs0 = (ch ^ ((r0 >> 1) & 3)) << 3;
    const int cs1 = (ch ^ ((r1 >> 1) & 3)) << 3;

#define STAGE2(buf, kt) { int k0 = (kt)*32; \
    gload_lds16(pa + (size_t)r0*K_A + k0 + cs0, &As[(buf)*4096 + t*8]); \
    gload_lds16(pa + (size_t)r1*K_A + k0 + cs1, &As[(buf)*4096 + (256+t)*8]); \
    gload_lds16(pb + (size_t)r0*K_A + k0 + cs0, &Bs[(buf)*4096 + t*8]); \
    gload_lds16(pb + (size_t)r1*K_A + k0 + cs1, &Bs[(buf)*4096 + (256+t)*8]); }

    STAGE2(0, 0);
    __syncthreads();
    int cur = 0;
    for (int kt = 0; kt < 16; ++kt){
        if (kt < 15) STAGE2(cur^1, kt+1);
        f16x8 af[4], bf[4], vf;
        vf = *(const f16x8*)&vsh[kt*32 + lq*8];
        #pragma unroll
        for (int mi = 0; mi < 4; ++mi){
            int r = wm + mi*16 + l15;
            af[mi] = *(const f16x8*)&As[cur*4096 + r*32 + ((lq ^ ((r>>1)&3)) << 3)];
        }
        #pragma unroll
        for (int ni = 0; ni < 4; ++ni){
            int r = wn + ni*16 + l15;
            bf[ni] = *(const f16x8*)&Bs[cur*4096 + r*32 + ((lq ^ ((r>>1)&3)) << 3)];
        }
        #pragma unroll
        for (int mi = 0; mi < 4; ++mi)
            #pragma unroll
            for (int ni = 0; ni < 4; ++ni)
                acc[mi][ni] = __builtin_amdgcn_mfma_f32_16x16x32_f16(af[mi], bf[ni], acc[mi][ni], 0, 0, 0);
        #pragma unroll
        for (int ni = 0; ni < 4; ++ni)
            racc[ni] = __builtin_amdgcn_mfma_f32_16x16x32_f16(vf, bf[ni], racc[ni], 0, 0, 0);
        __syncthreads();
        cur ^= 1;
    }
    float un[4];
    #pragma unroll
    for (int ni = 0; ni < 4; ++ni){
        float rv = racc[ni][0];
        float uo = u[nb*HW + nbase + wn + ni*16 + l15];
        un[ni] = uo / fmaxf(uo * rv, EPS_SK);
    }
    #pragma unroll
    for (int mi = 0; mi < 4; ++mi)
        #pragma unroll
        for (int ni = 0; ni < 4; ++ni)
            #pragma unroll
            for (int r = 0; r < 4; ++r){
                int c  = mbase + wm + mi*16 + lq*4 + r;
                int hw = nbase + wn + ni*16 + l15;
                out[((size_t)(nb*C_DIM + c))*HW + hw] = acc[mi][ni][r] * un[ni];
            }
}

extern "C" void kernel_launch(void* const* d_in, const int* in_sizes, int n_in,
                              void* d_out, int out_size, void* d_ws, size_t ws_size,
                              hipStream_t stream){
    const float* x  = (const float*)d_in[0];
    const int* sidx = (const int*)d_in[1];
    float* out = (float*)d_out;

    char* ws = (char*)d_ws;
    _Float16* Lt  = (_Float16*)ws;  ws += (size_t)N_B*HW*C_DIM*2;      // 32 MiB
    _Float16* A0  = (_Float16*)ws;  ws += (size_t)M_TOT*K_A*2;         // 64 MiB
    _Float16* sxT = (_Float16*)ws;  ws += (size_t)N_B*K_A*C_DIM*2;     // 4 MiB
    _Float16* SXv = (_Float16*)ws;  ws += (size_t)N_B*C_DIM*K_A*2;     // 4 MiB
    float*    u   = (float*)ws;     ws += (size_t)M_TOT*4;
    float*    v   = (float*)ws;     ws += (size_t)K_A*4;
    float*    part= (float*)ws;     ws += (size_t)1024*K_A*4;          // 2 MiB

    k_init     <<<256, 256, 0, stream>>>(u, v);
    k_normtrans<<<1024, 256, 0, stream>>>(x, Lt);
    k_gather   <<<dim3(64,16), 256, 0, stream>>>(Lt, sidx, sxT);
    k_gemm1    <<<dim3(32,4,16), 256, 0, stream>>>(Lt, sxT, A0, part);

    k_colfinish<<<512, 64, 0, stream>>>(part, v, 512);
    for (int it = 0; it < 3; ++it){
        k_fused    <<<1024, 256, 0, stream>>>(A0, v, u, part);
        k_colfinish<<<512, 64, 0, stream>>>(part, v, 1024);
    }

    k_sxvT <<<dim3(8,4,16), 256, 0, stream>>>(sxT, v, SXv);
    k_gemm2<<<dim3(2,32,16), 256, 0, stream>>>(SXv, A0, v, u, out);
}

// Round 6
// 157.377 us; speedup vs baseline: 2.2378x; 1.1091x over previous
//
#include <hip/hip_runtime.h>
#include <hip/hip_bf16.h>
#include <hip/hip_fp16.h>

#define N_B 16
#define C_DIM 256
#define HW 4096
#define M_TOT (N_B*HW)          // 65536 global rows
#define K_A 512
#define TEMP_INV (1.0f/0.3f)
#define EPS_SK 1e-12f

typedef _Float16 f16x8 __attribute__((ext_vector_type(8)));
typedef _Float16 f16x4 __attribute__((ext_vector_type(4)));
typedef float f32x4 __attribute__((ext_vector_type(4)));

#define GLOBAL_AS __attribute__((address_space(1)))
#define LDS_AS __attribute__((address_space(3)))
__device__ __forceinline__ void gload_lds16(const void* g, void* l){
    __builtin_amdgcn_global_load_lds((GLOBAL_AS const void*)g, (LDS_AS void*)l, 16, 0, 0);
}

// ---------------- fused: read x once -> L2 norm -> Lt[n][hw][c] fp16; also init u=1,v=1 ----------------
__global__ __launch_bounds__(256) void k_normtrans(const float* __restrict__ x,
                                                   _Float16* __restrict__ Lt,
                                                   float* __restrict__ u,
                                                   float* __restrict__ v){
    __shared__ float tl[64][257];
    __shared__ float red[4][64];
    __shared__ float invs[64];
    int n   = blockIdx.x >> 6;
    int hw0 = (blockIdx.x & 63) * 64;
    if (threadIdx.x < 64) u[blockIdx.x*64 + threadIdx.x] = 1.0f;
    if (blockIdx.x < 2)   v[blockIdx.x*256 + threadIdx.x] = 1.0f;
    int tx4 = threadIdx.x & 15;
    int cy  = threadIdx.x >> 4;
    const float* px = x + ((size_t)(n*C_DIM + cy))*HW + hw0 + tx4*4;
    #pragma unroll
    for (int r = 0; r < 16; ++r){
        float4 xv = *(const float4*)(px + (size_t)(r*16)*HW);
        int c = cy + r*16;
        tl[tx4*4+0][c] = xv.x;
        tl[tx4*4+1][c] = xv.y;
        tl[tx4*4+2][c] = xv.z;
        tl[tx4*4+3][c] = xv.w;
    }
    __syncthreads();
    int tx = threadIdx.x & 63, ty = threadIdx.x >> 6;
    float ss = 0.f;
    #pragma unroll
    for (int cc = 0; cc < 64; ++cc){
        float tv = tl[tx][cc*4 + ty];
        ss += tv*tv;
    }
    red[ty][tx] = ss;
    __syncthreads();
    if (ty == 0){
        float s = red[0][tx]+red[1][tx]+red[2][tx]+red[3][tx];
        invs[tx] = 1.0f / fmaxf(sqrtf(s), 1e-12f);
    }
    __syncthreads();
    #pragma unroll
    for (int r = 0; r < 16; ++r){
        int hwl = ty + r*4;
        float inv = invs[hwl];
        float4 a = *(const float4*)&tl[hwl][tx*4];
        f16x4 h;
        h[0] = (_Float16)(a.x*inv); h[1] = (_Float16)(a.y*inv);
        h[2] = (_Float16)(a.z*inv); h[3] = (_Float16)(a.w*inv);
        *(f16x4*)&Lt[((size_t)(n*HW + hw0 + hwl))*C_DIM + tx*4] = h;
    }
}

// ---------------- gather anchors from Lt (coalesced): sxT[n][j][c] fp16 ----------------
__global__ __launch_bounds__(256) void k_gather(const _Float16* __restrict__ Lt,
                                                const int* __restrict__ sidx,
                                                _Float16* __restrict__ sxT){
    int n  = blockIdx.y;
    int jj = blockIdx.x*8 + (threadIdx.x >> 5);
    int c8 = (threadIdx.x & 31) * 8;
    int p  = sidx[jj];
    *(f16x8*)&sxT[((size_t)(n*K_A + jj))*C_DIM + c8] =
        *(const f16x8*)&Lt[((size_t)(n*HW + p))*C_DIM + c8];
}

// ======== GEMM1 + first Sinkhorn column partials ========
// 128x128 tile, BK=32, 3-deep ring LDS, counted vmcnt (T4), XCD-swizzled 1D grid (T1).
__global__ __launch_bounds__(256) void k_gemm1(const _Float16* __restrict__ Lt,
                                               const _Float16* __restrict__ sxT,
                                               _Float16* __restrict__ A0,
                                               float* __restrict__ part){
    __shared__ _Float16 As[3*128*32];
    __shared__ _Float16 Bs[3*128*32];
    __shared__ float colred[4][128];
    // XCD swizzle: nwg=2048, 256 per XCD chunk; decode with jb innermost (Lt-tile shared by 4 jb)
    const int swz = (blockIdx.x & 7)*256 + (blockIdx.x >> 3);
    const int jb = swz & 3, mb = (swz >> 2) & 31, nb = swz >> 7;
    const int mbase = mb * 128;
    const int jbase = jb * 128;
    const int t = threadIdx.x;
    const int lane = t & 63, w = t >> 6;
    const int wm = (w >> 1)*64, wn = (w & 1)*64;
    const int l15 = lane & 15, lq = lane >> 4;

    f32x4 acc[4][4] = {};
    const _Float16* pa = Lt  + ((size_t)(nb*HW  + mbase))*C_DIM;
    const _Float16* pb = sxT + ((size_t)(nb*K_A + jbase))*C_DIM;

    const int r0 = t >> 2, ch = t & 3;
    const int r1 = r0 + 64;
    const int cs0 = (ch ^ ((r0 >> 1) & 3)) << 3;
    const int cs1 = (ch ^ ((r1 >> 1) & 3)) << 3;

#define STAGE1(buf, kt) { int k0 = (kt)*32; \
    gload_lds16(pa + (size_t)r0*C_DIM + k0 + cs0, &As[(buf)*4096 + t*8]); \
    gload_lds16(pa + (size_t)r1*C_DIM + k0 + cs1, &As[(buf)*4096 + (256+t)*8]); \
    gload_lds16(pb + (size_t)r0*C_DIM + k0 + cs0, &Bs[(buf)*4096 + t*8]); \
    gload_lds16(pb + (size_t)r1*C_DIM + k0 + cs1, &Bs[(buf)*4096 + (256+t)*8]); }

    STAGE1(0, 0); STAGE1(1, 1); STAGE1(2, 2);
    #pragma unroll
    for (int kt = 0; kt < 8; ++kt){
        // wait for step kt's loads: allow (steps in flight beyond kt) * 4 outstanding
        if (kt < 6)      asm volatile("s_waitcnt vmcnt(8)" ::: "memory");
        else if (kt < 7) asm volatile("s_waitcnt vmcnt(4)" ::: "memory");
        else             asm volatile("s_waitcnt vmcnt(0)" ::: "memory");
        __builtin_amdgcn_s_barrier();
        __builtin_amdgcn_sched_barrier(0);
        const int cur = kt % 3;
        f16x8 af[4], bf[4];
        #pragma unroll
        for (int mi = 0; mi < 4; ++mi){
            int r = wm + mi*16 + l15;
            af[mi] = *(const f16x8*)&As[cur*4096 + r*32 + ((lq ^ ((r>>1)&3)) << 3)];
        }
        #pragma unroll
        for (int ni = 0; ni < 4; ++ni){
            int r = wn + ni*16 + l15;
            bf[ni] = *(const f16x8*)&Bs[cur*4096 + r*32 + ((lq ^ ((r>>1)&3)) << 3)];
        }
        #pragma unroll
        for (int mi = 0; mi < 4; ++mi)
            #pragma unroll
            for (int ni = 0; ni < 4; ++ni)
                acc[mi][ni] = __builtin_amdgcn_mfma_f32_16x16x32_f16(af[mi], bf[ni], acc[mi][ni], 0, 0, 0);
        __builtin_amdgcn_s_barrier();
        __builtin_amdgcn_sched_barrier(0);
        if (kt < 5) STAGE1((kt+3)%3, kt+3);
    }
    float csum[4] = {0.f, 0.f, 0.f, 0.f};
    #pragma unroll
    for (int mi = 0; mi < 4; ++mi)
        #pragma unroll
        for (int ni = 0; ni < 4; ++ni)
            #pragma unroll
            for (int r = 0; r < 4; ++r){
                int hw = mbase + wm + mi*16 + lq*4 + r;
                int j  = jbase + wn + ni*16 + l15;
                float e = __expf(acc[mi][ni][r] * TEMP_INV);
                A0[((size_t)(nb*HW + hw))*K_A + j] = (_Float16)e;
                csum[ni] += e;
            }
    #pragma unroll
    for (int ni = 0; ni < 4; ++ni){
        float cv = csum[ni];
        cv += __shfl_xor(cv, 16);
        cv += __shfl_xor(cv, 32);
        if (lane < 16) colred[w][wn + ni*16 + l15] = cv;
    }
    __syncthreads();
    if (t < 128){
        int jj = t;
        float s = (jj < 64) ? (colred[0][jj] + colred[2][jj])
                            : (colred[1][jj] + colred[3][jj]);
        part[((size_t)(nb*32 + mb))*K_A + jbase + jj] = s;
    }
}

// v[j] <- 128 * v[j] / max(v[j]*S_j, EPS); S_j summed over nchunks partials
__global__ __launch_bounds__(64) void k_colfinish(const float* __restrict__ part,
                                                  float* __restrict__ v, int nchunks){
    int j = blockIdx.x;
    int lane = threadIdx.x;
    float s = 0.f;
    for (int r = lane; r < nchunks; r += 64) s += part[(size_t)r*K_A + j];
    #pragma unroll
    for (int off = 32; off; off >>= 1) s += __shfl_xor(s, off);
    if (lane == 0){
        float vo = v[j];
        v[j] = 128.0f * vo / fmaxf(vo * s, EPS_SK);
    }
}

// ---------------- FUSED: row-update u (from v) + next column partials (one A0 read) ----------------
__global__ __launch_bounds__(256) void k_fused(const _Float16* __restrict__ A0,
                                               const float* __restrict__ v,
                                               float* __restrict__ u,
                                               float* __restrict__ part){
    __shared__ float red[4][512];
    int b = blockIdx.x;                         // 1024 blocks, 64 rows each
    int tg = threadIdx.x >> 6, lane = threadIdx.x & 63;
    float vr[8];
    const float* pv = v + (lane << 3);
    #pragma unroll
    for (int e = 0; e < 8; ++e) vr[e] = pv[e];
    float acc[8] = {};
    for (int it = 0; it < 16; ++it){
        int i = (b << 6) + (it << 2) + tg;
        f16x8 a = *(const f16x8*)&A0[(size_t)i*K_A + (lane << 3)];
        float r = 0.f;
        #pragma unroll
        for (int e = 0; e < 8; ++e) r += (float)a[e] * vr[e];
        #pragma unroll
        for (int off = 32; off; off >>= 1) r += __shfl_xor(r, off);
        float uo = u[i];
        float un = uo / fmaxf(uo * r, EPS_SK);
        if (lane == 0) u[i] = un;
        #pragma unroll
        for (int e = 0; e < 8; ++e) acc[e] += (float)a[e] * un;
    }
    #pragma unroll
    for (int e = 0; e < 8; ++e) red[tg][(lane<<3)+e] = acc[e];
    __syncthreads();
    if (tg == 0){
        #pragma unroll
        for (int e = 0; e < 8; ++e){
            int j = (lane<<3)+e;
            part[((size_t)b)*K_A + j] = red[0][j]+red[1][j]+red[2][j]+red[3][j];
        }
    }
}

// ---------------- SXv[n][c][j] = sxT[n][j][c] * v[j]  (LDS transpose, fp16) ----------------
__global__ __launch_bounds__(256) void k_sxvT(const _Float16* __restrict__ sxT,
                                              const float* __restrict__ v,
                                              _Float16* __restrict__ SXv){
    __shared__ float tl[64][65];
    int n  = blockIdx.z;
    int j0 = blockIdx.x * 64;
    int c0 = blockIdx.y * 64;
    int tx = threadIdx.x & 63, ty = threadIdx.x >> 6;
    #pragma unroll
    for (int r = 0; r < 16; ++r){
        int jl = ty + r*4;
        tl[jl][tx] = (float)sxT[((size_t)(n*K_A + j0 + jl))*C_DIM + c0 + tx] * v[j0 + jl];
    }
    __syncthreads();
    #pragma unroll
    for (int r = 0; r < 16; ++r){
        int cl = ty + r*4;
        SXv[((size_t)(n*C_DIM + c0 + cl))*K_A + j0 + tx] = (_Float16)tl[tx][cl];
    }
}

// ======== GEMM2 + final row-normalize ========
// out = u4[hw]*sum_j SXv[c][j]*A0[hw][j]; u4 via racc MFMA (v-broadcast A-frag).
// 3-deep ring + counted vmcnt + XCD swizzle (mb innermost: A0-tile shared by mb pair).
__global__ __launch_bounds__(256) void k_gemm2(const _Float16* __restrict__ SXv,
                                               const _Float16* __restrict__ A0,
                                               const float* __restrict__ v,
                                               const float* __restrict__ u,
                                               float* __restrict__ out){
    __shared__ _Float16 As[3*128*32];
    __shared__ _Float16 Bs[3*128*32];
    __shared__ _Float16 vsh[512];
    // nwg=1024, 128 per XCD chunk; mb innermost so (mb=0,1) share the A0 B-tile in one L2
    const int swz = (blockIdx.x & 7)*128 + (blockIdx.x >> 3);
    const int mb = swz & 1, nbi = (swz >> 1) & 31, nb = swz >> 6;
    const int mbase = mb * 128;    // c
    const int nbase = nbi * 128;   // hw
    const int t = threadIdx.x;
    const int lane = t & 63, w = t >> 6;
    const int wm = (w >> 1)*64, wn = (w & 1)*64;
    const int l15 = lane & 15, lq = lane >> 4;

    vsh[t]       = (_Float16)v[t];
    vsh[t + 256] = (_Float16)v[t + 256];

    f32x4 acc[4][4] = {};
    f32x4 racc[4] = {};
    const _Float16* pa = SXv + ((size_t)(nb*C_DIM + mbase))*K_A;
    const _Float16* pb = A0  + ((size_t)(nb*HW   + nbase))*K_A;

    const int r0 = t >> 2, ch = t & 3;
    const int r1 = r0 + 64;
    const int cs0 = (ch ^ ((r0 >> 1) & 3)) << 3;
    const int cs1 = (ch ^ ((r1 >> 1) & 3)) << 3;

#define STAGE2(buf, kt) { int k0 = (kt)*32; \
    gload_lds16(pa + (size_t)r0*K_A + k0 + cs0, &As[(buf)*4096 + t*8]); \
    gload_lds16(pa + (size_t)r1*K_A + k0 + cs1, &As[(buf)*4096 + (256+t)*8]); \
    gload_lds16(pb + (size_t)r0*K_A + k0 + cs0, &Bs[(buf)*4096 + t*8]); \
    gload_lds16(pb + (size_t)r1*K_A + k0 + cs1, &Bs[(buf)*4096 + (256+t)*8]); }

    STAGE2(0, 0); STAGE2(1, 1); STAGE2(2, 2);
    #pragma unroll
    for (int kt = 0; kt < 16; ++kt){
        if (kt < 14)      asm volatile("s_waitcnt vmcnt(8)" ::: "memory");
        else if (kt < 15) asm volatile("s_waitcnt vmcnt(4)" ::: "memory");
        else              asm volatile("s_waitcnt vmcnt(0)" ::: "memory");
        __builtin_amdgcn_s_barrier();
        __builtin_amdgcn_sched_barrier(0);
        const int cur = kt % 3;
        f16x8 af[4], bf[4], vf;
        vf = *(const f16x8*)&vsh[kt*32 + lq*8];
        #pragma unroll
        for (int mi = 0; mi < 4; ++mi){
            int r = wm + mi*16 + l15;
            af[mi] = *(const f16x8*)&As[cur*4096 + r*32 + ((lq ^ ((r>>1)&3)) << 3)];
        }
        #pragma unroll
        for (int ni = 0; ni < 4; ++ni){
            int r = wn + ni*16 + l15;
            bf[ni] = *(const f16x8*)&Bs[cur*4096 + r*32 + ((lq ^ ((r>>1)&3)) << 3)];
        }
        #pragma unroll
        for (int mi = 0; mi < 4; ++mi)
            #pragma unroll
            for (int ni = 0; ni < 4; ++ni)
                acc[mi][ni] = __builtin_amdgcn_mfma_f32_16x16x32_f16(af[mi], bf[ni], acc[mi][ni], 0, 0, 0);
        #pragma unroll
        for (int ni = 0; ni < 4; ++ni)
            racc[ni] = __builtin_amdgcn_mfma_f32_16x16x32_f16(vf, bf[ni], racc[ni], 0, 0, 0);
        __builtin_amdgcn_s_barrier();
        __builtin_amdgcn_sched_barrier(0);
        if (kt < 13) STAGE2((kt+3)%3, kt+3);
    }
    float un[4];
    #pragma unroll
    for (int ni = 0; ni < 4; ++ni){
        float rv = racc[ni][0];
        float uo = u[nb*HW + nbase + wn + ni*16 + l15];
        un[ni] = uo / fmaxf(uo * rv, EPS_SK);
    }
    #pragma unroll
    for (int mi = 0; mi < 4; ++mi)
        #pragma unroll
        for (int ni = 0; ni < 4; ++ni)
            #pragma unroll
            for (int r = 0; r < 4; ++r){
                int c  = mbase + wm + mi*16 + lq*4 + r;
                int hw = nbase + wn + ni*16 + l15;
                out[((size_t)(nb*C_DIM + c))*HW + hw] = acc[mi][ni][r] * un[ni];
            }
}

extern "C" void kernel_launch(void* const* d_in, const int* in_sizes, int n_in,
                              void* d_out, int out_size, void* d_ws, size_t ws_size,
                              hipStream_t stream){
    const float* x  = (const float*)d_in[0];
    const int* sidx = (const int*)d_in[1];
    float* out = (float*)d_out;

    char* ws = (char*)d_ws;
    _Float16* Lt  = (_Float16*)ws;  ws += (size_t)N_B*HW*C_DIM*2;      // 32 MiB
    _Float16* A0  = (_Float16*)ws;  ws += (size_t)M_TOT*K_A*2;         // 64 MiB
    _Float16* sxT = (_Float16*)ws;  ws += (size_t)N_B*K_A*C_DIM*2;     // 4 MiB
    _Float16* SXv = (_Float16*)ws;  ws += (size_t)N_B*C_DIM*K_A*2;     // 4 MiB
    float*    u   = (float*)ws;     ws += (size_t)M_TOT*4;
    float*    v   = (float*)ws;     ws += (size_t)K_A*4;
    float*    part= (float*)ws;     ws += (size_t)1024*K_A*4;          // 2 MiB

    k_normtrans<<<1024, 256, 0, stream>>>(x, Lt, u, v);
    k_gather   <<<dim3(64,16), 256, 0, stream>>>(Lt, sidx, sxT);
    k_gemm1    <<<2048, 256, 0, stream>>>(Lt, sxT, A0, part);

    k_colfinish<<<512, 64, 0, stream>>>(part, v, 512);
    for (int it = 0; it < 3; ++it){
        k_fused    <<<1024, 256, 0, stream>>>(A0, v, u, part);
        k_colfinish<<<512, 64, 0, stream>>>(part, v, 1024);
    }

    k_sxvT <<<dim3(8,4,16), 256, 0, stream>>>(sxT, v, SXv);
    k_gemm2<<<1024, 256, 0, stream>>>(SXv, A0, v, u, out);
}